// Round 1
// baseline (5473.189 us; speedup 1.0000x reference)
//
#include <hip/hip_runtime.h>

// DeepM3Model: 200-step GRU+RK4 scan (B=1024,S=200,H=256) + head GEMM to 50000 items.
// Inputs/outputs are fp32 (confirmed: bf16 reads gave NaN; fp32-out decode matches
// round-2 error signature). On-device dtype sniff retained as a safety net.
// Pipeline: sniff -> canon weights to bf16 -> dt -> gi table (item_emb@Wih^T+bih,
// fp32 preferred) -> persistent WG-local scan (64 WGs x 16 batch rows, 9 barriers/step,
// W1/W2 resident in VGPRs, fp32 h with bf16 hi/lo through Whh MFMA) -> head GEMM.
//
// R1 changes (theory: allocator sank w1f/w2f loads into the RK4 loops at 128 VGPRs):
//  - amdgpu_waves_per_eu(2,2) on scan_kernel: unlock 256-VGPR budget so W1/W2 stay
//    register-resident and the Whh stream can pipeline.
//  - gi gathers prefetched one step ahead into registers (indices independent of h).
//  - nontemporal table gathers: stop evicting Whh/W1/W2 from per-XCD L2.
//  - x / dt staged into LDS once at kernel start (removes per-step global loads).

#define B_SZ   1024
#define S_LEN  200
#define HD     256
#define NITEMS 50000
#define NPAD   50048

// canonical weight block offsets (u16 elements)
#define OFF_WHH 0
#define OFF_WIH 196608
#define OFF_W1  393216
#define OFF_W2  458752
#define OFF_BHH 524288
#define OFF_BIH 525056
#define OFF_B1  525824
#define OFF_B2  526080
#define CANON_N 526336

typedef short short8 __attribute__((ext_vector_type(8)));
typedef float f32x4  __attribute__((ext_vector_type(4)));

__device__ __forceinline__ float bf2f(unsigned short u){
  unsigned v = ((unsigned)u) << 16; float f; __builtin_memcpy(&f, &v, 4); return f;
}
__device__ __forceinline__ unsigned short f2bf(float f){
  unsigned u; __builtin_memcpy(&u, &f, 4);
  u += 0x7FFFu + ((u >> 16) & 1u);            // round-to-nearest-even
  return (unsigned short)(u >> 16);
}
__device__ __forceinline__ float fsig(float x){ return 1.0f / (1.0f + __expf(-x)); }
__device__ __forceinline__ float ftanh(float x){
  float e = __expf(-2.0f * fabsf(x));
  float r = (1.0f - e) / (1.0f + e);
  return copysignf(r, x);
}
__device__ __forceinline__ f32x4 MFMA(short8 a, short8 b, f32x4 c){
  return __builtin_amdgcn_mfma_f32_16x16x32_bf16(a, b, c, 0, 0, 0);
}
// fragment-order LDS layout for a [16 rows x 256 k] bf16 plane:
// 16B unit index = kc*16 + ((row^kc)&15)  -> conflict-free b128 reads/writes
__device__ __forceinline__ int foff(int kc, int row){
  return (kc * 16 + ((row ^ kc) & 15)) * 8;  // element (short) index
}

// ---------------- dtype sniff: t sorted in [0,10]; bf16 u16 <= 0x4120 always.
__global__ void sniff_kernel(const unsigned short* __restrict__ t, int* __restrict__ flag){
  int lane = threadIdx.x & 63;
  int bad = 0;
#pragma unroll
  for (int q = 0; q < 8; ++q)
    if (t[lane * 8 + q] > 0x4200u) bad = 1;
  unsigned long long m = __ballot(bad);
  if (lane == 0) flag[0] = (m != 0ull) ? 1 : 0;
}

// ---------------- canonicalize small weights to bf16
__global__ void conv_kernel(const int* __restrict__ flag,
    const void* __restrict__ Whh, const void* __restrict__ Wih,
    const void* __restrict__ W1,  const void* __restrict__ W2,
    const void* __restrict__ bhh, const void* __restrict__ bih,
    const void* __restrict__ b1,  const void* __restrict__ b2,
    unsigned short* __restrict__ dst)
{
  int i = blockIdx.x * 256 + threadIdx.x;
  if (i >= CANON_N) return;
  int f32m = flag[0];
  const void* src; int off = i;
  if (i < OFF_WIH)      { src = Whh; off = i - OFF_WHH; }
  else if (i < OFF_W1)  { src = Wih; off = i - OFF_WIH; }
  else if (i < OFF_W2)  { src = W1;  off = i - OFF_W1; }
  else if (i < OFF_BHH) { src = W2;  off = i - OFF_W2; }
  else if (i < OFF_BIH) { src = bhh; off = i - OFF_BHH; }
  else if (i < OFF_B1)  { src = bih; off = i - OFF_BIH; }
  else if (i < OFF_B2)  { src = b1;  off = i - OFF_B1; }
  else                  { src = b2;  off = i - OFF_B2; }
  unsigned short v = f32m ? f2bf(((const float*)src)[off])
                          : ((const unsigned short*)src)[off];
  dst[i] = v;
}

// ---------------- W_head -> bf16 (4 elements per thread)
__global__ void convw_kernel(const int* __restrict__ flag,
    const void* __restrict__ Wh, unsigned short* __restrict__ dst)
{
  int i4 = blockIdx.x * 256 + threadIdx.x;
  if (i4 * 4 >= NITEMS * HD) return;
  if (flag[0]){
    f32x4 v = ((const f32x4*)Wh)[i4];
#pragma unroll
    for (int q = 0; q < 4; ++q) dst[i4 * 4 + q] = f2bf(v[q]);
  } else {
    ((unsigned long long*)dst)[i4] = ((const unsigned long long*)Wh)[i4];
  }
}

// ---------------- dt precompute
__global__ void dt_kernel(const void* __restrict__ t, const int* __restrict__ flag,
                          float* __restrict__ dt){
  int i = blockIdx.x * 256 + threadIdx.x;
  if (i >= B_SZ * S_LEN) return;
  int f32m = flag[0];
  int s = i % S_LEN;
  float tc = f32m ? ((const float*)t)[i] : bf2f(((const unsigned short*)t)[i]);
  float d = 0.0f;
  if (s < S_LEN - 1){
    float tn = f32m ? ((const float*)t)[i + 1] : bf2f(((const unsigned short*)t)[i + 1]);
    d = fmaxf(tn, tc + 1e-5f) - tc;
  }
  dt[i] = d;
}

// ---------------- G[i, j] = sum_k emb[i,k] * Wih[j,k] + bih[j]   (i<50000, j<768)
__global__ __launch_bounds__(256) void gitems_kernel(
    const void* __restrict__ emb, const unsigned short* __restrict__ canon,
    const int* __restrict__ flag, void* __restrict__ tbl, int tblf32)
{
  __shared__ __align__(16) short ap[4][4096];    // 4 row-tiles x [16x256] bf16
  const int tid = threadIdx.x;
  const int i0 = blockIdx.x * 64;
  const int n0 = blockIdx.y * 256;
  const int f32m = flag[0];
  {
    int kc = tid & 31, r8 = tid >> 5;
#pragma unroll
    for (int p = 0; p < 8; ++p){
      int row = p * 8 + r8;
      int gr = i0 + row; if (gr > NITEMS - 1) gr = NITEMS - 1;
      short8 v;
      if (f32m){
        const f32x4* src = (const f32x4*)((const float*)emb + gr * HD + kc * 8);
        f32x4 v0 = src[0], v1 = src[1];
#pragma unroll
        for (int q = 0; q < 4; ++q){ v[q] = (short)f2bf(v0[q]); v[4+q] = (short)f2bf(v1[q]); }
      } else {
        v = *(const short8*)((const unsigned short*)emb + gr * HD + kc * 8);
      }
      *(short8*)&ap[row >> 4][foff(kc, row & 15)] = v;
    }
  }
  __syncthreads();
  const int wave = tid >> 6, lane = tid & 63, col = lane & 15, quad = lane >> 4;
  const unsigned short* Wih = canon + OFF_WIH;
  const unsigned short* bih = canon + OFF_BIH;
  f32x4 zz = {0.0f, 0.0f, 0.0f, 0.0f};
  f32x4 acc[4][4];
#pragma unroll
  for (int rt = 0; rt < 4; ++rt)
#pragma unroll
    for (int ct = 0; ct < 4; ++ct) acc[rt][ct] = zz;

#pragma unroll
  for (int ks = 0; ks < 8; ++ks){
    short8 bf[4];
#pragma unroll
    for (int ct = 0; ct < 4; ++ct){
      int n = n0 + wave * 64 + ct * 16 + col;
      bf[ct] = *(const short8*)(Wih + n * HD + ks * 32 + quad * 8);
    }
    int kc = ks * 4 + quad;
#pragma unroll
    for (int rt = 0; rt < 4; ++rt){
      short8 a = *(const short8*)&ap[rt][foff(kc, col)];
#pragma unroll
      for (int ct = 0; ct < 4; ++ct) acc[rt][ct] = MFMA(a, bf[ct], acc[rt][ct]);
    }
  }
  float bv[4];
#pragma unroll
  for (int ct = 0; ct < 4; ++ct) bv[ct] = bf2f(bih[n0 + wave * 64 + ct * 16 + col]);
  float* tfo = (float*)tbl; unsigned short* tbo = (unsigned short*)tbl;
#pragma unroll
  for (int rt = 0; rt < 4; ++rt)
#pragma unroll
    for (int ct = 0; ct < 4; ++ct)
#pragma unroll
      for (int r = 0; r < 4; ++r){
        int row = i0 + rt * 16 + quad * 4 + r;
        if (row < NITEMS){
          int n = n0 + wave * 64 + ct * 16 + col;
          float v = acc[rt][ct][r] + bv[ct];
          if (tblf32) tfo[row * 768 + n] = v;
          else        tbo[row * 768 + n] = (unsigned short)f2bf(v);
        }
      }
}

// ---------------- persistent scan: 64 WGs x 512 thr; WG owns 16 batch rows.
// waves_per_eu(2,2): pin allocator to the full 256-VGPR budget (2 waves/EU is the
// natural occupancy of an 8-wave block at 1 WG/CU) -- at the default it targeted
// 4 waves/EU (128 VGPRs == exactly the w1f+w2f footprint) and sank the weight
// loads into the RK4 loops, serializing an L2/L3 load per MFMA.
__global__ __launch_bounds__(512) __attribute__((amdgpu_waves_per_eu(2, 2)))
void scan_kernel(
    const int* __restrict__ x, const float* __restrict__ dtp,
    const unsigned short* __restrict__ canon,
    const void* __restrict__ tbl, int tblf32,
    float* __restrict__ hstate)
{
  __shared__ __align__(16) short bufhi[2][4096];   // ping-pong A planes (bf16 hi)
  __shared__ __align__(16) short buflo[2][4096];   // lo plane (h state only)
  __shared__ __align__(16) int   xl[16 * S_LEN];   // item indices, staged once
  __shared__ __align__(16) float dtall[16 * S_LEN];// dt, staged once

  const int tid  = threadIdx.x;
  const int wave = tid >> 6;
  const int lane = tid & 63;
  const int col  = lane & 15;        // A-row / C-col lane index
  const int quad = lane >> 4;
  const int r0   = blockIdx.x * 16;  // batch rows owned by this WG
  const int wc0  = wave * 32;        // hidden-col base for this wave (2 tiles of 16)

  const unsigned short* Whh = canon + OFF_WHH;
  const unsigned short* W1w = canon + OFF_W1;
  const unsigned short* W2w = canon + OFF_W2;
  const unsigned short* bhh = canon + OFF_BHH;
  const unsigned short* b1v = canon + OFF_B1;
  const unsigned short* b2v = canon + OFF_B2;

  { // zero initial h buffer (buf 0): h0 = 0
    short8 z = {0,0,0,0,0,0,0,0};
    *(short8*)&bufhi[0][tid * 8] = z;
    *(short8*)&buflo[0][tid * 8] = z;
  }
  // stage x / dt for this WG's 16 rows (contiguous, coalesced)
  for (int i = tid; i < 16 * S_LEN; i += 512){
    xl[i]    = x[r0 * S_LEN + i];
    dtall[i] = dtp[r0 * S_LEN + i];
  }

  // resident W1/W2 fragments: 128 VGPRs/wave -> RK4 matmuls need no global loads
  short8 w1f[2][8], w2f[2][8];
#pragma unroll
  for (int ct = 0; ct < 2; ++ct){
    int n = wc0 + ct * 16 + col;
#pragma unroll
    for (int ks = 0; ks < 8; ++ks){
      w1f[ct][ks] = *(const short8*)(W1w + n * HD + ks * 32 + quad * 8);
      w2f[ct][ks] = *(const short8*)(W2w + n * HD + ks * 32 + quad * 8);
    }
  }
  float bR[2], bZ[2], bN[2], b1c[2], b2c[2];
#pragma unroll
  for (int ct = 0; ct < 2; ++ct){
    int c = wc0 + ct * 16 + col;
    bR[ct]  = bf2f(bhh[c]);          bZ[ct] = bf2f(bhh[HD + c]);
    bN[ct]  = bf2f(bhh[2 * HD + c]);
    b1c[ct] = bf2f(b1v[c]);          b2c[ct] = bf2f(b2v[c]);
  }

  float h[2][4];
#pragma unroll
  for (int ct = 0; ct < 2; ++ct)
#pragma unroll
    for (int r = 0; r < 4; ++r) h[ct][r] = 0.0f;

  const float* tf = (const float*)tbl;
  const unsigned short* tb = (const unsigned short*)tbl;

  __syncthreads();

  // gather prefetch for s=0 (nontemporal: keep the weight set L2-resident)
  float gR[2][4], gZ[2][4], gN[2][4];
#pragma unroll
  for (int r = 0; r < 4; ++r){
    long base = (long)xl[(quad * 4 + r) * S_LEN] * 768;
#pragma unroll
    for (int ct = 0; ct < 2; ++ct){
      int c = wc0 + ct * 16 + col;
      if (tblf32){
        gR[ct][r] = __builtin_nontemporal_load(tf + base + c);
        gZ[ct][r] = __builtin_nontemporal_load(tf + base + 256 + c);
        gN[ct][r] = __builtin_nontemporal_load(tf + base + 512 + c);
      } else {
        gR[ct][r] = bf2f(__builtin_nontemporal_load(tb + base + c));
        gZ[ct][r] = bf2f(__builtin_nontemporal_load(tb + base + 256 + c));
        gN[ct][r] = bf2f(__builtin_nontemporal_load(tb + base + 512 + c));
      }
    }
  }

  for (int s = 0; s < S_LEN; ++s){
    const int pb = s & 1;
    float dtr[4];
#pragma unroll
    for (int r = 0; r < 4; ++r) dtr[r] = dtall[(quad * 4 + r) * S_LEN + s];

    // ---- stage 0: gh = h @ Whh^T (hi/lo split A), acc pre-init from prefetched gi
    f32x4 aR[2], aZ[2], aN[2];
    float giN[2][4];
#pragma unroll
    for (int ct = 0; ct < 2; ++ct)
#pragma unroll
      for (int r = 0; r < 4; ++r){
        aR[ct][r] = gR[ct][r];
        aZ[ct][r] = gZ[ct][r];
        aN[ct][r] = 0.0f;          // i_n separate: r gates only h-part
        giN[ct][r] = gN[ct][r];
      }

    // issue next step's gathers now; they complete during the 8 RK4 stages
    {
      int sn = (s + 1 < S_LEN) ? s + 1 : S_LEN - 1;
#pragma unroll
      for (int r = 0; r < 4; ++r){
        long base = (long)xl[(quad * 4 + r) * S_LEN + sn] * 768;
#pragma unroll
        for (int ct = 0; ct < 2; ++ct){
          int c = wc0 + ct * 16 + col;
          if (tblf32){
            gR[ct][r] = __builtin_nontemporal_load(tf + base + c);
            gZ[ct][r] = __builtin_nontemporal_load(tf + base + 256 + c);
            gN[ct][r] = __builtin_nontemporal_load(tf + base + 512 + c);
          } else {
            gR[ct][r] = bf2f(__builtin_nontemporal_load(tb + base + c));
            gZ[ct][r] = bf2f(__builtin_nontemporal_load(tb + base + 256 + c));
            gN[ct][r] = bf2f(__builtin_nontemporal_load(tb + base + 512 + c));
          }
        }
      }
    }

#pragma unroll
    for (int ks = 0; ks < 8; ++ks){
      int kc = ks * 4 + quad;
      short8 ahi = *(const short8*)&bufhi[pb][foff(kc, col)];
      short8 alo = *(const short8*)&buflo[pb][foff(kc, col)];
#pragma unroll
      for (int ct = 0; ct < 2; ++ct){
        int nb = wc0 + ct * 16 + col;
        short8 b0 = *(const short8*)(Whh + (0 * HD + nb) * HD + ks * 32 + quad * 8);
        aR[ct] = MFMA(ahi, b0, aR[ct]); aR[ct] = MFMA(alo, b0, aR[ct]);
        short8 b1f = *(const short8*)(Whh + (1 * HD + nb) * HD + ks * 32 + quad * 8);
        aZ[ct] = MFMA(ahi, b1f, aZ[ct]); aZ[ct] = MFMA(alo, b1f, aZ[ct]);
        short8 b2f = *(const short8*)(Whh + (2 * HD + nb) * HD + ks * 32 + quad * 8);
        aN[ct] = MFMA(ahi, b2f, aN[ct]); aN[ct] = MFMA(alo, b2f, aN[ct]);
      }
    }
    // gates + GRU update (fp32)
    float hg[2][4], ksum[2][4];
#pragma unroll
    for (int ct = 0; ct < 2; ++ct)
#pragma unroll
      for (int r = 0; r < 4; ++r){
        int row = quad * 4 + r;
        float rr = fsig(aR[ct][r] + bR[ct]);
        float z_ = fsig(aZ[ct][r] + bZ[ct]);
        float nn = ftanh(giN[ct][r] + rr * (aN[ct][r] + bN[ct]));
        float hgv = (1.0f - z_) * nn + z_ * h[ct][r];
        hg[ct][r] = hgv;
        int c = wc0 + ct * 16 + col;
        bufhi[1 - pb][foff(c >> 3, row) + (c & 7)] = (short)f2bf(hgv);
      }
    __syncthreads();                                   // barrier 1

    // ---- RK4: 4 x (u = tanh(y@W1^T+b1); k = u@W2^T+b2)
#pragma unroll
    for (int j = 0; j < 4; ++j){
      // u-stage: read buf[1-pb], write buf[pb]
      f32x4 ua[2];
      ua[0] = (f32x4){b1c[0], b1c[0], b1c[0], b1c[0]};
      ua[1] = (f32x4){b1c[1], b1c[1], b1c[1], b1c[1]};
#pragma unroll
      for (int ks = 0; ks < 8; ++ks){
        int kc = ks * 4 + quad;
        short8 a = *(const short8*)&bufhi[1 - pb][foff(kc, col)];
        ua[0] = MFMA(a, w1f[0][ks], ua[0]);
        ua[1] = MFMA(a, w1f[1][ks], ua[1]);
      }
#pragma unroll
      for (int ct = 0; ct < 2; ++ct)
#pragma unroll
        for (int r = 0; r < 4; ++r){
          int row = quad * 4 + r, c = wc0 + ct * 16 + col;
          bufhi[pb][foff(c >> 3, row) + (c & 7)] = (short)f2bf(ftanh(ua[ct][r]));
        }
      __syncthreads();

      // k-stage: read buf[pb], write buf[1-pb]
      f32x4 ka[2];
      ka[0] = (f32x4){b2c[0], b2c[0], b2c[0], b2c[0]};
      ka[1] = (f32x4){b2c[1], b2c[1], b2c[1], b2c[1]};
#pragma unroll
      for (int ks = 0; ks < 8; ++ks){
        int kc = ks * 4 + quad;
        short8 a = *(const short8*)&bufhi[pb][foff(kc, col)];
        ka[0] = MFMA(a, w2f[0][ks], ka[0]);
        ka[1] = MFMA(a, w2f[1][ks], ka[1]);
      }
#pragma unroll
      for (int ct = 0; ct < 2; ++ct)
#pragma unroll
        for (int r = 0; r < 4; ++r){
          int row = quad * 4 + r;
          float dtv = dtr[r];
          float kv = ka[ct][r];
          int c = wc0 + ct * 16 + col;
          if (j == 0){
            ksum[ct][r] = kv;
            float y = hg[ct][r] + 0.5f * dtv * kv;
            bufhi[1 - pb][foff(c >> 3, row) + (c & 7)] = (short)f2bf(y);
          } else if (j == 1){
            ksum[ct][r] += 2.0f * kv;
            float y = hg[ct][r] + 0.5f * dtv * kv;
            bufhi[1 - pb][foff(c >> 3, row) + (c & 7)] = (short)f2bf(y);
          } else if (j == 2){
            ksum[ct][r] += 2.0f * kv;
            float y = hg[ct][r] + dtv * kv;
            bufhi[1 - pb][foff(c >> 3, row) + (c & 7)] = (short)f2bf(y);
          } else {
            ksum[ct][r] += kv;
            float hn = hg[ct][r] + (dtv * (1.0f / 6.0f)) * ksum[ct][r];
            h[ct][r] = hn;
            unsigned short hh = f2bf(hn);
            float fh = bf2f(hh);
            unsigned short hl = f2bf(hn - fh);       // hi/lo split for next step's gh
            bufhi[1 - pb][foff(c >> 3, row) + (c & 7)] = (short)hh;
            buflo[1 - pb][foff(c >> 3, row) + (c & 7)] = (short)hl;
          }
        }
      __syncthreads();
    }
  }
  // store final h (fp32)
#pragma unroll
  for (int ct = 0; ct < 2; ++ct)
#pragma unroll
    for (int r = 0; r < 4; ++r){
      int row = quad * 4 + r;
      hstate[(r0 + row) * HD + wc0 + ct * 16 + col] = h[ct][r];
    }
}

// ---------------- head: out[b,n] = sum_k h[b,k]*Whead[n,k] + bhead[n]
// out dtype follows flag (fp32 normally, bf16 fallback).
__global__ __launch_bounds__(256) void head_kernel(
    const float* __restrict__ hstate,
    const unsigned short* __restrict__ Whb,   // preconverted bf16 (wbf=1) or null path
    const void* __restrict__ Wh,              // original W_head
    const void* __restrict__ bh, const int* __restrict__ flag, int wbf,
    void* __restrict__ outv)
{
  __shared__ __align__(16) short ahi[4][4096];
  __shared__ __align__(16) short alo[4][4096];
  const int tid = threadIdx.x;
  const int i0 = blockIdx.x * 64;
  const int n0 = blockIdx.y * 256;
  const int f32m = flag[0];
  {
    int kc = tid & 31, r8 = tid >> 5;
#pragma unroll
    for (int p = 0; p < 8; ++p){
      int row = p * 8 + r8;
      const float* src = hstate + (i0 + row) * HD + kc * 8;
      short8 vh, vl;
#pragma unroll
      for (int q = 0; q < 8; ++q){
        float f = src[q];
        unsigned short hb = f2bf(f);
        float fh = bf2f(hb);
        vh[q] = (short)hb; vl[q] = (short)f2bf(f - fh);
      }
      int off = foff(kc, row & 15);
      *(short8*)&ahi[row >> 4][off] = vh;
      *(short8*)&alo[row >> 4][off] = vl;
    }
  }
  __syncthreads();
  const int wave = tid >> 6, lane = tid & 63, col = lane & 15, quad = lane >> 4;
  f32x4 zz = {0.0f, 0.0f, 0.0f, 0.0f};
  f32x4 acc[4][4];
#pragma unroll
  for (int rt = 0; rt < 4; ++rt)
#pragma unroll
    for (int ct = 0; ct < 4; ++ct) acc[rt][ct] = zz;

  int nidx[4];
#pragma unroll
  for (int ct = 0; ct < 4; ++ct){
    int n = n0 + wave * 64 + ct * 16 + col;
    nidx[ct] = (n < NITEMS) ? n : (NITEMS - 1);
  }
#pragma unroll
  for (int ks = 0; ks < 8; ++ks){
    short8 bf[4];
#pragma unroll
    for (int ct = 0; ct < 4; ++ct){
      if (wbf){
        bf[ct] = *(const short8*)(Whb + nidx[ct] * HD + ks * 32 + quad * 8);
      } else if (f32m){
        const f32x4* src = (const f32x4*)((const float*)Wh + nidx[ct] * HD + ks * 32 + quad * 8);
        f32x4 v0 = src[0], v1 = src[1];
        short8 v;
#pragma unroll
        for (int q = 0; q < 4; ++q){ v[q] = (short)f2bf(v0[q]); v[4+q] = (short)f2bf(v1[q]); }
        bf[ct] = v;
      } else {
        bf[ct] = *(const short8*)((const unsigned short*)Wh + nidx[ct] * HD + ks * 32 + quad * 8);
      }
    }
    int kc = ks * 4 + quad;
#pragma unroll
    for (int rt = 0; rt < 4; ++rt){
      short8 xh = *(const short8*)&ahi[rt][foff(kc, col)];
      short8 xl = *(const short8*)&alo[rt][foff(kc, col)];
#pragma unroll
      for (int ct = 0; ct < 4; ++ct){
        acc[rt][ct] = MFMA(xh, bf[ct], acc[rt][ct]);
        acc[rt][ct] = MFMA(xl, bf[ct], acc[rt][ct]);
      }
    }
  }
  float bhv[4];
#pragma unroll
  for (int ct = 0; ct < 4; ++ct)
    bhv[ct] = f32m ? ((const float*)bh)[nidx[ct]] : bf2f(((const unsigned short*)bh)[nidx[ct]]);
  float* outf = (float*)outv;
  unsigned short* outb = (unsigned short*)outv;
#pragma unroll
  for (int rt = 0; rt < 4; ++rt)
#pragma unroll
    for (int ct = 0; ct < 4; ++ct)
#pragma unroll
      for (int r = 0; r < 4; ++r){
        int row = i0 + rt * 16 + quad * 4 + r;
        int n = n0 + wave * 64 + ct * 16 + col;
        if (n < NITEMS){
          float v = acc[rt][ct][r] + bhv[ct];
          long o = (long)row * NITEMS + n;
          if (f32m) outf[o] = v;
          else      outb[o] = (unsigned short)f2bf(v);
        }
      }
}

extern "C" void kernel_launch(void* const* d_in, const int* in_sizes, int n_in,
                              void* d_out, int out_size, void* d_ws, size_t ws_size,
                              hipStream_t stream) {
  const int*  x     = (const int*)d_in[0];
  const void* t     = d_in[1];
  const void* emb   = d_in[2];
  const void* Wih   = d_in[3];
  const void* Whh   = d_in[4];
  const void* bih   = d_in[5];
  const void* bhh   = d_in[6];
  const void* W1    = d_in[7];
  const void* b1    = d_in[8];
  const void* W2    = d_in[9];
  const void* b2    = d_in[10];
  const void* Whead = d_in[11];
  const void* bhead = d_in[12];

  char* ws = (char*)d_ws;
  int*   flag   = (int*)(ws);                              // @0      (4 B)
  float* dtbuf  = (float*)(ws + 4096);                     // 819200 B
  float* hstate = (float*)(ws + (1u << 20));               // 1 MB @ +1MB
  unsigned short* canon = (unsigned short*)(ws + (2u << 20));   // ~1.01 MB @ +2MB
  unsigned short* wheadb = (unsigned short*)(ws + (4u << 20));  // 25.6 MB @ +4MB
  const size_t tbase = 32u << 20;                          // table @ +32MB
  const size_t TBL_F32  = (size_t)NPAD * 768 * 4;          // 153.7 MB
  const size_t TBL_BF16 = (size_t)NPAD * 768 * 2;          // 76.9 MB

  int wbf = (ws_size >= (32u << 20)) ? 1 : 0;
  void* tbl; int tblf32;
  if (ws_size >= tbase + TBL_F32)       { tbl = (void*)(ws + tbase); tblf32 = 1; }
  else if (ws_size >= tbase + TBL_BF16) { tbl = (void*)(ws + tbase); tblf32 = 0; }
  else                                  { tbl = (void*)d_out;        tblf32 = 0; } // d_out(204.8MB fp32) as scratch; head overwrites

  sniff_kernel<<<dim3(1), dim3(64), 0, stream>>>((const unsigned short*)t, flag);
  conv_kernel<<<dim3((CANON_N + 255) / 256), dim3(256), 0, stream>>>(
      flag, Whh, Wih, W1, W2, bhh, bih, b1, b2, canon);
  if (wbf)
    convw_kernel<<<dim3((NITEMS * HD / 4 + 255) / 256), dim3(256), 0, stream>>>(
        flag, Whead, wheadb);
  dt_kernel<<<dim3((B_SZ * S_LEN + 255) / 256), dim3(256), 0, stream>>>(t, flag, dtbuf);
  gitems_kernel<<<dim3(NPAD / 64, 3), dim3(256), 0, stream>>>(emb, canon, flag, tbl, tblf32);
  scan_kernel<<<dim3(64), dim3(512), 0, stream>>>(x, dtbuf, canon, tbl, tblf32, hstate);
  head_kernel<<<dim3(B_SZ / 64, (NITEMS + 255) / 256), dim3(256), 0, stream>>>(
      hstate, wheadb, Whead, bhead, flag, wbf, d_out);
}

// Round 3
// 5381.661 us; speedup vs baseline: 1.0170x; 1.0170x over previous
//
#include <hip/hip_runtime.h>

// DeepM3Model: 200-step GRU+RK4 scan (B=1024,S=200,H=256) + head GEMM to 50000 items.
// Inputs/outputs are fp32 (confirmed: bf16 reads gave NaN; fp32-out decode matches
// round-2 error signature). On-device dtype sniff retained as a safety net.
// Pipeline: sniff -> canon weights to bf16 -> dt -> gi table (item_emb@Wih^T+bih,
// fp32 preferred) -> persistent WG-local scan (64 WGs x 16 batch rows, 9 barriers/step,
// W1/W2 resident in VGPRs, fp32 h with bf16 hi/lo through Whh MFMA) -> head GEMM.
//
// R3 = R2 retry with the documented register-budget knob. Theory (R1 evidence):
// VGPR_Count pinned at 128 == exactly the w1f+w2f footprint, 0.5 GB scratch-spill
// writes -> RA budget too small; weight fragments not resident; every RK4 MFMA fed
// by a serialized global load. Fix: __launch_bounds__(512, 2) (min 2 waves/EU ->
// 256-VGPR budget) + 40 KB LDS occupancy pad (99 KB total -> 1 WG/CU -> backend's
// LDS-derived occupancy also 2 waves/EU). amdgpu_waves_per_eu attribute removed
// (proven ignored in R1; possible toolchain risk in R2's container failure).

#define B_SZ   1024
#define S_LEN  200
#define HD     256
#define NITEMS 50000
#define NPAD   50048

// canonical weight block offsets (u16 elements)
#define OFF_WHH 0
#define OFF_WIH 196608
#define OFF_W1  393216
#define OFF_W2  458752
#define OFF_BHH 524288
#define OFF_BIH 525056
#define OFF_B1  525824
#define OFF_B2  526080
#define CANON_N 526336

typedef short short8 __attribute__((ext_vector_type(8)));
typedef float f32x4  __attribute__((ext_vector_type(4)));

__device__ __forceinline__ float bf2f(unsigned short u){
  unsigned v = ((unsigned)u) << 16; float f; __builtin_memcpy(&f, &v, 4); return f;
}
__device__ __forceinline__ unsigned short f2bf(float f){
  unsigned u; __builtin_memcpy(&u, &f, 4);
  u += 0x7FFFu + ((u >> 16) & 1u);            // round-to-nearest-even
  return (unsigned short)(u >> 16);
}
__device__ __forceinline__ float fsig(float x){ return 1.0f / (1.0f + __expf(-x)); }
__device__ __forceinline__ float ftanh(float x){
  float e = __expf(-2.0f * fabsf(x));
  float r = (1.0f - e) / (1.0f + e);
  return copysignf(r, x);
}
__device__ __forceinline__ f32x4 MFMA(short8 a, short8 b, f32x4 c){
  return __builtin_amdgcn_mfma_f32_16x16x32_bf16(a, b, c, 0, 0, 0);
}
// fragment-order LDS layout for a [16 rows x 256 k] bf16 plane:
// 16B unit index = kc*16 + ((row^kc)&15)  -> conflict-free b128 reads/writes
__device__ __forceinline__ int foff(int kc, int row){
  return (kc * 16 + ((row ^ kc) & 15)) * 8;  // element (short) index
}

// ---------------- dtype sniff: t sorted in [0,10]; bf16 u16 <= 0x4120 always.
__global__ void sniff_kernel(const unsigned short* __restrict__ t, int* __restrict__ flag){
  int lane = threadIdx.x & 63;
  int bad = 0;
#pragma unroll
  for (int q = 0; q < 8; ++q)
    if (t[lane * 8 + q] > 0x4200u) bad = 1;
  unsigned long long m = __ballot(bad);
  if (lane == 0) flag[0] = (m != 0ull) ? 1 : 0;
}

// ---------------- canonicalize small weights to bf16
__global__ void conv_kernel(const int* __restrict__ flag,
    const void* __restrict__ Whh, const void* __restrict__ Wih,
    const void* __restrict__ W1,  const void* __restrict__ W2,
    const void* __restrict__ bhh, const void* __restrict__ bih,
    const void* __restrict__ b1,  const void* __restrict__ b2,
    unsigned short* __restrict__ dst)
{
  int i = blockIdx.x * 256 + threadIdx.x;
  if (i >= CANON_N) return;
  int f32m = flag[0];
  const void* src; int off = i;
  if (i < OFF_WIH)      { src = Whh; off = i - OFF_WHH; }
  else if (i < OFF_W1)  { src = Wih; off = i - OFF_WIH; }
  else if (i < OFF_W2)  { src = W1;  off = i - OFF_W1; }
  else if (i < OFF_BHH) { src = W2;  off = i - OFF_W2; }
  else if (i < OFF_BIH) { src = bhh; off = i - OFF_BHH; }
  else if (i < OFF_B1)  { src = bih; off = i - OFF_BIH; }
  else if (i < OFF_B2)  { src = b1;  off = i - OFF_B1; }
  else                  { src = b2;  off = i - OFF_B2; }
  unsigned short v = f32m ? f2bf(((const float*)src)[off])
                          : ((const unsigned short*)src)[off];
  dst[i] = v;
}

// ---------------- W_head -> bf16 (4 elements per thread)
__global__ void convw_kernel(const int* __restrict__ flag,
    const void* __restrict__ Wh, unsigned short* __restrict__ dst)
{
  int i4 = blockIdx.x * 256 + threadIdx.x;
  if (i4 * 4 >= NITEMS * HD) return;
  if (flag[0]){
    f32x4 v = ((const f32x4*)Wh)[i4];
#pragma unroll
    for (int q = 0; q < 4; ++q) dst[i4 * 4 + q] = f2bf(v[q]);
  } else {
    ((unsigned long long*)dst)[i4] = ((const unsigned long long*)Wh)[i4];
  }
}

// ---------------- dt precompute
__global__ void dt_kernel(const void* __restrict__ t, const int* __restrict__ flag,
                          float* __restrict__ dt){
  int i = blockIdx.x * 256 + threadIdx.x;
  if (i >= B_SZ * S_LEN) return;
  int f32m = flag[0];
  int s = i % S_LEN;
  float tc = f32m ? ((const float*)t)[i] : bf2f(((const unsigned short*)t)[i]);
  float d = 0.0f;
  if (s < S_LEN - 1){
    float tn = f32m ? ((const float*)t)[i + 1] : bf2f(((const unsigned short*)t)[i + 1]);
    d = fmaxf(tn, tc + 1e-5f) - tc;
  }
  dt[i] = d;
}

// ---------------- G[i, j] = sum_k emb[i,k] * Wih[j,k] + bih[j]   (i<50000, j<768)
__global__ __launch_bounds__(256) void gitems_kernel(
    const void* __restrict__ emb, const unsigned short* __restrict__ canon,
    const int* __restrict__ flag, void* __restrict__ tbl, int tblf32)
{
  __shared__ __align__(16) short ap[4][4096];    // 4 row-tiles x [16x256] bf16
  const int tid = threadIdx.x;
  const int i0 = blockIdx.x * 64;
  const int n0 = blockIdx.y * 256;
  const int f32m = flag[0];
  {
    int kc = tid & 31, r8 = tid >> 5;
#pragma unroll
    for (int p = 0; p < 8; ++p){
      int row = p * 8 + r8;
      int gr = i0 + row; if (gr > NITEMS - 1) gr = NITEMS - 1;
      short8 v;
      if (f32m){
        const f32x4* src = (const f32x4*)((const float*)emb + gr * HD + kc * 8);
        f32x4 v0 = src[0], v1 = src[1];
#pragma unroll
        for (int q = 0; q < 4; ++q){ v[q] = (short)f2bf(v0[q]); v[4+q] = (short)f2bf(v1[q]); }
      } else {
        v = *(const short8*)((const unsigned short*)emb + gr * HD + kc * 8);
      }
      *(short8*)&ap[row >> 4][foff(kc, row & 15)] = v;
    }
  }
  __syncthreads();
  const int wave = tid >> 6, lane = tid & 63, col = lane & 15, quad = lane >> 4;
  const unsigned short* Wih = canon + OFF_WIH;
  const unsigned short* bih = canon + OFF_BIH;
  f32x4 zz = {0.0f, 0.0f, 0.0f, 0.0f};
  f32x4 acc[4][4];
#pragma unroll
  for (int rt = 0; rt < 4; ++rt)
#pragma unroll
    for (int ct = 0; ct < 4; ++ct) acc[rt][ct] = zz;

#pragma unroll
  for (int ks = 0; ks < 8; ++ks){
    short8 bf[4];
#pragma unroll
    for (int ct = 0; ct < 4; ++ct){
      int n = n0 + wave * 64 + ct * 16 + col;
      bf[ct] = *(const short8*)(Wih + n * HD + ks * 32 + quad * 8);
    }
    int kc = ks * 4 + quad;
#pragma unroll
    for (int rt = 0; rt < 4; ++rt){
      short8 a = *(const short8*)&ap[rt][foff(kc, col)];
#pragma unroll
      for (int ct = 0; ct < 4; ++ct) acc[rt][ct] = MFMA(a, bf[ct], acc[rt][ct]);
    }
  }
  float bv[4];
#pragma unroll
  for (int ct = 0; ct < 4; ++ct) bv[ct] = bf2f(bih[n0 + wave * 64 + ct * 16 + col]);
  float* tfo = (float*)tbl; unsigned short* tbo = (unsigned short*)tbl;
#pragma unroll
  for (int rt = 0; rt < 4; ++rt)
#pragma unroll
    for (int ct = 0; ct < 4; ++ct)
#pragma unroll
      for (int r = 0; r < 4; ++r){
        int row = i0 + rt * 16 + quad * 4 + r;
        if (row < NITEMS){
          int n = n0 + wave * 64 + ct * 16 + col;
          float v = acc[rt][ct][r] + bv[ct];
          if (tblf32) tfo[row * 768 + n] = v;
          else        tbo[row * 768 + n] = (unsigned short)f2bf(v);
        }
      }
}

// ---------------- persistent scan: 64 WGs x 512 thr; WG owns 16 batch rows.
// __launch_bounds__(512, 2): min 2 waves/EU -> RA budget 256 VGPRs (documented
// HIP knob; second arg is min waves per EU). LDS pad (99 KB total) additionally
// forces 1 WG/CU so the backend's LDS-derived occupancy agrees. Grid is 64 WGs
// on 256 CUs, so 1 WG/CU costs nothing at runtime.
__global__ __launch_bounds__(512, 2)
void scan_kernel(
    const int* __restrict__ x, const float* __restrict__ dtp,
    const unsigned short* __restrict__ canon,
    const void* __restrict__ tbl, int tblf32, int pad_use,
    float* __restrict__ hstate)
{
  __shared__ __align__(16) short bufhi[2][4096];   // ping-pong A planes (bf16 hi)
  __shared__ __align__(16) short buflo[2][4096];   // lo plane (h state only)
  __shared__ __align__(16) int   xl[16 * S_LEN];   // item indices, staged once
  __shared__ __align__(16) float dtall[16 * S_LEN];// dt, staged once
  __shared__ __align__(16) char  pad_occ[40960];   // occupancy pad (never touched)

  const int tid  = threadIdx.x;
  const int wave = tid >> 6;
  const int lane = tid & 63;
  const int col  = lane & 15;        // A-row / C-col lane index
  const int quad = lane >> 4;
  const int r0   = blockIdx.x * 16;  // batch rows owned by this WG
  const int wc0  = wave * 32;        // hidden-col base for this wave (2 tiles of 16)

  if (pad_use){                       // pad_use==0 at runtime; opaque to compiler
    pad_occ[tid * 80] = (char)tid;
    if (pad_occ[0] == 37) hstate[0] = 0.0f;
  }

  const unsigned short* Whh = canon + OFF_WHH;
  const unsigned short* W1w = canon + OFF_W1;
  const unsigned short* W2w = canon + OFF_W2;
  const unsigned short* bhh = canon + OFF_BHH;
  const unsigned short* b1v = canon + OFF_B1;
  const unsigned short* b2v = canon + OFF_B2;

  { // zero initial h buffer (buf 0): h0 = 0
    short8 z = {0,0,0,0,0,0,0,0};
    *(short8*)&bufhi[0][tid * 8] = z;
    *(short8*)&buflo[0][tid * 8] = z;
  }
  // stage x / dt for this WG's 16 rows (contiguous, coalesced)
  for (int i = tid; i < 16 * S_LEN; i += 512){
    xl[i]    = x[r0 * S_LEN + i];
    dtall[i] = dtp[r0 * S_LEN + i];
  }

  // resident W1/W2 fragments: 128 VGPRs/wave -> RK4 matmuls need no global loads
  short8 w1f[2][8], w2f[2][8];
#pragma unroll
  for (int ct = 0; ct < 2; ++ct){
    int n = wc0 + ct * 16 + col;
#pragma unroll
    for (int ks = 0; ks < 8; ++ks){
      w1f[ct][ks] = *(const short8*)(W1w + n * HD + ks * 32 + quad * 8);
      w2f[ct][ks] = *(const short8*)(W2w + n * HD + ks * 32 + quad * 8);
    }
  }
  float bR[2], bZ[2], bN[2], b1c[2], b2c[2];
#pragma unroll
  for (int ct = 0; ct < 2; ++ct){
    int c = wc0 + ct * 16 + col;
    bR[ct]  = bf2f(bhh[c]);          bZ[ct] = bf2f(bhh[HD + c]);
    bN[ct]  = bf2f(bhh[2 * HD + c]);
    b1c[ct] = bf2f(b1v[c]);          b2c[ct] = bf2f(b2v[c]);
  }

  float h[2][4];
#pragma unroll
  for (int ct = 0; ct < 2; ++ct)
#pragma unroll
    for (int r = 0; r < 4; ++r) h[ct][r] = 0.0f;

  const float* tf = (const float*)tbl;
  const unsigned short* tb = (const unsigned short*)tbl;

  __syncthreads();

  // gather prefetch for s=0 (nontemporal: keep the weight set L2-resident)
  float gR[2][4], gZ[2][4], gN[2][4];
#pragma unroll
  for (int r = 0; r < 4; ++r){
    long base = (long)xl[(quad * 4 + r) * S_LEN] * 768;
#pragma unroll
    for (int ct = 0; ct < 2; ++ct){
      int c = wc0 + ct * 16 + col;
      if (tblf32){
        gR[ct][r] = __builtin_nontemporal_load(tf + base + c);
        gZ[ct][r] = __builtin_nontemporal_load(tf + base + 256 + c);
        gN[ct][r] = __builtin_nontemporal_load(tf + base + 512 + c);
      } else {
        gR[ct][r] = bf2f(__builtin_nontemporal_load(tb + base + c));
        gZ[ct][r] = bf2f(__builtin_nontemporal_load(tb + base + 256 + c));
        gN[ct][r] = bf2f(__builtin_nontemporal_load(tb + base + 512 + c));
      }
    }
  }

  for (int s = 0; s < S_LEN; ++s){
    const int pb = s & 1;
    float dtr[4];
#pragma unroll
    for (int r = 0; r < 4; ++r) dtr[r] = dtall[(quad * 4 + r) * S_LEN + s];

    // ---- stage 0: gh = h @ Whh^T (hi/lo split A), acc pre-init from prefetched gi
    f32x4 aR[2], aZ[2], aN[2];
    float giN[2][4];
#pragma unroll
    for (int ct = 0; ct < 2; ++ct)
#pragma unroll
      for (int r = 0; r < 4; ++r){
        aR[ct][r] = gR[ct][r];
        aZ[ct][r] = gZ[ct][r];
        aN[ct][r] = 0.0f;          // i_n separate: r gates only h-part
        giN[ct][r] = gN[ct][r];
      }

    // issue next step's gathers now; they complete during the 8 RK4 stages
    {
      int sn = (s + 1 < S_LEN) ? s + 1 : S_LEN - 1;
#pragma unroll
      for (int r = 0; r < 4; ++r){
        long base = (long)xl[(quad * 4 + r) * S_LEN + sn] * 768;
#pragma unroll
        for (int ct = 0; ct < 2; ++ct){
          int c = wc0 + ct * 16 + col;
          if (tblf32){
            gR[ct][r] = __builtin_nontemporal_load(tf + base + c);
            gZ[ct][r] = __builtin_nontemporal_load(tf + base + 256 + c);
            gN[ct][r] = __builtin_nontemporal_load(tf + base + 512 + c);
          } else {
            gR[ct][r] = bf2f(__builtin_nontemporal_load(tb + base + c));
            gZ[ct][r] = bf2f(__builtin_nontemporal_load(tb + base + 256 + c));
            gN[ct][r] = bf2f(__builtin_nontemporal_load(tb + base + 512 + c));
          }
        }
      }
    }

#pragma unroll
    for (int ks = 0; ks < 8; ++ks){
      int kc = ks * 4 + quad;
      short8 ahi = *(const short8*)&bufhi[pb][foff(kc, col)];
      short8 alo = *(const short8*)&buflo[pb][foff(kc, col)];
#pragma unroll
      for (int ct = 0; ct < 2; ++ct){
        int nb = wc0 + ct * 16 + col;
        short8 b0 = *(const short8*)(Whh + (0 * HD + nb) * HD + ks * 32 + quad * 8);
        aR[ct] = MFMA(ahi, b0, aR[ct]); aR[ct] = MFMA(alo, b0, aR[ct]);
        short8 b1f = *(const short8*)(Whh + (1 * HD + nb) * HD + ks * 32 + quad * 8);
        aZ[ct] = MFMA(ahi, b1f, aZ[ct]); aZ[ct] = MFMA(alo, b1f, aZ[ct]);
        short8 b2f = *(const short8*)(Whh + (2 * HD + nb) * HD + ks * 32 + quad * 8);
        aN[ct] = MFMA(ahi, b2f, aN[ct]); aN[ct] = MFMA(alo, b2f, aN[ct]);
      }
    }
    // gates + GRU update (fp32)
    float hg[2][4], ksum[2][4];
#pragma unroll
    for (int ct = 0; ct < 2; ++ct)
#pragma unroll
      for (int r = 0; r < 4; ++r){
        int row = quad * 4 + r;
        float rr = fsig(aR[ct][r] + bR[ct]);
        float z_ = fsig(aZ[ct][r] + bZ[ct]);
        float nn = ftanh(giN[ct][r] + rr * (aN[ct][r] + bN[ct]));
        float hgv = (1.0f - z_) * nn + z_ * h[ct][r];
        hg[ct][r] = hgv;
        int c = wc0 + ct * 16 + col;
        bufhi[1 - pb][foff(c >> 3, row) + (c & 7)] = (short)f2bf(hgv);
      }
    __syncthreads();                                   // barrier 1

    // ---- RK4: 4 x (u = tanh(y@W1^T+b1); k = u@W2^T+b2)
#pragma unroll
    for (int j = 0; j < 4; ++j){
      // u-stage: read buf[1-pb], write buf[pb]
      f32x4 ua[2];
      ua[0] = (f32x4){b1c[0], b1c[0], b1c[0], b1c[0]};
      ua[1] = (f32x4){b1c[1], b1c[1], b1c[1], b1c[1]};
#pragma unroll
      for (int ks = 0; ks < 8; ++ks){
        int kc = ks * 4 + quad;
        short8 a = *(const short8*)&bufhi[1 - pb][foff(kc, col)];
        ua[0] = MFMA(a, w1f[0][ks], ua[0]);
        ua[1] = MFMA(a, w1f[1][ks], ua[1]);
      }
#pragma unroll
      for (int ct = 0; ct < 2; ++ct)
#pragma unroll
        for (int r = 0; r < 4; ++r){
          int row = quad * 4 + r, c = wc0 + ct * 16 + col;
          bufhi[pb][foff(c >> 3, row) + (c & 7)] = (short)f2bf(ftanh(ua[ct][r]));
        }
      __syncthreads();

      // k-stage: read buf[pb], write buf[1-pb]
      f32x4 ka[2];
      ka[0] = (f32x4){b2c[0], b2c[0], b2c[0], b2c[0]};
      ka[1] = (f32x4){b2c[1], b2c[1], b2c[1], b2c[1]};
#pragma unroll
      for (int ks = 0; ks < 8; ++ks){
        int kc = ks * 4 + quad;
        short8 a = *(const short8*)&bufhi[pb][foff(kc, col)];
        ka[0] = MFMA(a, w2f[0][ks], ka[0]);
        ka[1] = MFMA(a, w2f[1][ks], ka[1]);
      }
#pragma unroll
      for (int ct = 0; ct < 2; ++ct)
#pragma unroll
        for (int r = 0; r < 4; ++r){
          int row = quad * 4 + r;
          float dtv = dtr[r];
          float kv = ka[ct][r];
          int c = wc0 + ct * 16 + col;
          if (j == 0){
            ksum[ct][r] = kv;
            float y = hg[ct][r] + 0.5f * dtv * kv;
            bufhi[1 - pb][foff(c >> 3, row) + (c & 7)] = (short)f2bf(y);
          } else if (j == 1){
            ksum[ct][r] += 2.0f * kv;
            float y = hg[ct][r] + 0.5f * dtv * kv;
            bufhi[1 - pb][foff(c >> 3, row) + (c & 7)] = (short)f2bf(y);
          } else if (j == 2){
            ksum[ct][r] += 2.0f * kv;
            float y = hg[ct][r] + dtv * kv;
            bufhi[1 - pb][foff(c >> 3, row) + (c & 7)] = (short)f2bf(y);
          } else {
            ksum[ct][r] += kv;
            float hn = hg[ct][r] + (dtv * (1.0f / 6.0f)) * ksum[ct][r];
            h[ct][r] = hn;
            unsigned short hh = f2bf(hn);
            float fh = bf2f(hh);
            unsigned short hl = f2bf(hn - fh);       // hi/lo split for next step's gh
            bufhi[1 - pb][foff(c >> 3, row) + (c & 7)] = (short)hh;
            buflo[1 - pb][foff(c >> 3, row) + (c & 7)] = (short)hl;
          }
        }
      __syncthreads();
    }
  }
  // store final h (fp32)
#pragma unroll
  for (int ct = 0; ct < 2; ++ct)
#pragma unroll
    for (int r = 0; r < 4; ++r){
      int row = quad * 4 + r;
      hstate[(r0 + row) * HD + wc0 + ct * 16 + col] = h[ct][r];
    }
}

// ---------------- head: out[b,n] = sum_k h[b,k]*Whead[n,k] + bhead[n]
// out dtype follows flag (fp32 normally, bf16 fallback).
__global__ __launch_bounds__(256) void head_kernel(
    const float* __restrict__ hstate,
    const unsigned short* __restrict__ Whb,   // preconverted bf16 (wbf=1) or null path
    const void* __restrict__ Wh,              // original W_head
    const void* __restrict__ bh, const int* __restrict__ flag, int wbf,
    void* __restrict__ outv)
{
  __shared__ __align__(16) short ahi[4][4096];
  __shared__ __align__(16) short alo[4][4096];
  const int tid = threadIdx.x;
  const int i0 = blockIdx.x * 64;
  const int n0 = blockIdx.y * 256;
  const int f32m = flag[0];
  {
    int kc = tid & 31, r8 = tid >> 5;
#pragma unroll
    for (int p = 0; p < 8; ++p){
      int row = p * 8 + r8;
      const float* src = hstate + (i0 + row) * HD + kc * 8;
      short8 vh, vl;
#pragma unroll
      for (int q = 0; q < 8; ++q){
        float f = src[q];
        unsigned short hb = f2bf(f);
        float fh = bf2f(hb);
        vh[q] = (short)hb; vl[q] = (short)f2bf(f - fh);
      }
      int off = foff(kc, row & 15);
      *(short8*)&ahi[row >> 4][off] = vh;
      *(short8*)&alo[row >> 4][off] = vl;
    }
  }
  __syncthreads();
  const int wave = tid >> 6, lane = tid & 63, col = lane & 15, quad = lane >> 4;
  f32x4 zz = {0.0f, 0.0f, 0.0f, 0.0f};
  f32x4 acc[4][4];
#pragma unroll
  for (int rt = 0; rt < 4; ++rt)
#pragma unroll
    for (int ct = 0; ct < 4; ++ct) acc[rt][ct] = zz;

  int nidx[4];
#pragma unroll
  for (int ct = 0; ct < 4; ++ct){
    int n = n0 + wave * 64 + ct * 16 + col;
    nidx[ct] = (n < NITEMS) ? n : (NITEMS - 1);
  }
#pragma unroll
  for (int ks = 0; ks < 8; ++ks){
    short8 bf[4];
#pragma unroll
    for (int ct = 0; ct < 4; ++ct){
      if (wbf){
        bf[ct] = *(const short8*)(Whb + nidx[ct] * HD + ks * 32 + quad * 8);
      } else if (f32m){
        const f32x4* src = (const f32x4*)((const float*)Wh + nidx[ct] * HD + ks * 32 + quad * 8);
        f32x4 v0 = src[0], v1 = src[1];
        short8 v;
#pragma unroll
        for (int q = 0; q < 4; ++q){ v[q] = (short)f2bf(v0[q]); v[4+q] = (short)f2bf(v1[q]); }
        bf[ct] = v;
      } else {
        bf[ct] = *(const short8*)((const unsigned short*)Wh + nidx[ct] * HD + ks * 32 + quad * 8);
      }
    }
    int kc = ks * 4 + quad;
#pragma unroll
    for (int rt = 0; rt < 4; ++rt){
      short8 xh = *(const short8*)&ahi[rt][foff(kc, col)];
      short8 xl = *(const short8*)&alo[rt][foff(kc, col)];
#pragma unroll
      for (int ct = 0; ct < 4; ++ct){
        acc[rt][ct] = MFMA(xh, bf[ct], acc[rt][ct]);
        acc[rt][ct] = MFMA(xl, bf[ct], acc[rt][ct]);
      }
    }
  }
  float bhv[4];
#pragma unroll
  for (int ct = 0; ct < 4; ++ct)
    bhv[ct] = f32m ? ((const float*)bh)[nidx[ct]] : bf2f(((const unsigned short*)bh)[nidx[ct]]);
  float* outf = (float*)outv;
  unsigned short* outb = (unsigned short*)outv;
#pragma unroll
  for (int rt = 0; rt < 4; ++rt)
#pragma unroll
    for (int ct = 0; ct < 4; ++ct)
#pragma unroll
      for (int r = 0; r < 4; ++r){
        int row = i0 + rt * 16 + quad * 4 + r;
        int n = n0 + wave * 64 + ct * 16 + col;
        if (n < NITEMS){
          float v = acc[rt][ct][r] + bhv[ct];
          long o = (long)row * NITEMS + n;
          if (f32m) outf[o] = v;
          else      outb[o] = (unsigned short)f2bf(v);
        }
      }
}

extern "C" void kernel_launch(void* const* d_in, const int* in_sizes, int n_in,
                              void* d_out, int out_size, void* d_ws, size_t ws_size,
                              hipStream_t stream) {
  const int*  x     = (const int*)d_in[0];
  const void* t     = d_in[1];
  const void* emb   = d_in[2];
  const void* Wih   = d_in[3];
  const void* Whh   = d_in[4];
  const void* bih   = d_in[5];
  const void* bhh   = d_in[6];
  const void* W1    = d_in[7];
  const void* b1    = d_in[8];
  const void* W2    = d_in[9];
  const void* b2    = d_in[10];
  const void* Whead = d_in[11];
  const void* bhead = d_in[12];

  char* ws = (char*)d_ws;
  int*   flag   = (int*)(ws);                              // @0      (4 B)
  float* dtbuf  = (float*)(ws + 4096);                     // 819200 B
  float* hstate = (float*)(ws + (1u << 20));               // 1 MB @ +1MB
  unsigned short* canon = (unsigned short*)(ws + (2u << 20));   // ~1.01 MB @ +2MB
  unsigned short* wheadb = (unsigned short*)(ws + (4u << 20));  // 25.6 MB @ +4MB
  const size_t tbase = 32u << 20;                          // table @ +32MB
  const size_t TBL_F32  = (size_t)NPAD * 768 * 4;          // 153.7 MB
  const size_t TBL_BF16 = (size_t)NPAD * 768 * 2;          // 76.9 MB

  int wbf = (ws_size >= (32u << 20)) ? 1 : 0;
  void* tbl; int tblf32;
  if (ws_size >= tbase + TBL_F32)       { tbl = (void*)(ws + tbase); tblf32 = 1; }
  else if (ws_size >= tbase + TBL_BF16) { tbl = (void*)(ws + tbase); tblf32 = 0; }
  else                                  { tbl = (void*)d_out;        tblf32 = 0; } // d_out(204.8MB fp32) as scratch; head overwrites

  sniff_kernel<<<dim3(1), dim3(64), 0, stream>>>((const unsigned short*)t, flag);
  conv_kernel<<<dim3((CANON_N + 255) / 256), dim3(256), 0, stream>>>(
      flag, Whh, Wih, W1, W2, bhh, bih, b1, b2, canon);
  if (wbf)
    convw_kernel<<<dim3((NITEMS * HD / 4 + 255) / 256), dim3(256), 0, stream>>>(
        flag, Whead, wheadb);
  dt_kernel<<<dim3((B_SZ * S_LEN + 255) / 256), dim3(256), 0, stream>>>(t, flag, dtbuf);
  gitems_kernel<<<dim3(NPAD / 64, 3), dim3(256), 0, stream>>>(emb, canon, flag, tbl, tblf32);
  scan_kernel<<<dim3(64), dim3(512), 0, stream>>>(x, dtbuf, canon, tbl, tblf32, 0, hstate);
  head_kernel<<<dim3(B_SZ / 64, (NITEMS + 255) / 256), dim3(256), 0, stream>>>(
      hstate, wheadb, Whead, bhead, flag, wbf, d_out);
}

// Round 4
// 4580.027 us; speedup vs baseline: 1.1950x; 1.1750x over previous
//
#include <hip/hip_runtime.h>

// DeepM3Model: 200-step GRU+RK4 scan (B=1024,S=200,H=256) + head GEMM to 50000 items.
// Inputs/outputs are fp32 (confirmed: bf16 reads gave NaN; fp32-out decode matches
// round-2 error signature). On-device dtype sniff retained as a safety net.
// Pipeline: sniff -> canon weights to bf16 -> dt -> gi table (item_emb@Wih^T+bih,
// fp32 preferred) -> persistent WG-local scan (64 WGs x 16 batch rows, 9 barriers/step,
// ALL weights streamed from L2, fp32 h with bf16 hi/lo through Whh MFMA) -> head GEMM.
//
// R4 theory: the resident w1f/w2f arrays (exactly 128 VGPRs) were the bottleneck,
// not the fix. R1/R3 proved the RA stays at 128 regs regardless of launch_bounds
// or LDS-derived occupancy; with the arrays claiming the whole file, weight loads
// were sunk serially into the MFMA loops and everything else spilled (387-514 MB
// scratch writes). R4 deletes the resident arrays: W1/W2 stream from L2 like Whh,
// register pressure drops to ~100, the compiler can batch the 16 independent
// B-fragment loads per stage ahead of the accumulator chain. NT gathers retained
// (R3 proved they keep the weight set L2-resident: FETCH 1.24 GB -> 0.77 GB).
// No pad, no register gather-prefetch (both hurt).

#define B_SZ   1024
#define S_LEN  200
#define HD     256
#define NITEMS 50000
#define NPAD   50048

// canonical weight block offsets (u16 elements)
#define OFF_WHH 0
#define OFF_WIH 196608
#define OFF_W1  393216
#define OFF_W2  458752
#define OFF_BHH 524288
#define OFF_BIH 525056
#define OFF_B1  525824
#define OFF_B2  526080
#define CANON_N 526336

typedef short short8 __attribute__((ext_vector_type(8)));
typedef float f32x4  __attribute__((ext_vector_type(4)));

__device__ __forceinline__ float bf2f(unsigned short u){
  unsigned v = ((unsigned)u) << 16; float f; __builtin_memcpy(&f, &v, 4); return f;
}
__device__ __forceinline__ unsigned short f2bf(float f){
  unsigned u; __builtin_memcpy(&u, &f, 4);
  u += 0x7FFFu + ((u >> 16) & 1u);            // round-to-nearest-even
  return (unsigned short)(u >> 16);
}
__device__ __forceinline__ float fsig(float x){ return 1.0f / (1.0f + __expf(-x)); }
__device__ __forceinline__ float ftanh(float x){
  float e = __expf(-2.0f * fabsf(x));
  float r = (1.0f - e) / (1.0f + e);
  return copysignf(r, x);
}
__device__ __forceinline__ f32x4 MFMA(short8 a, short8 b, f32x4 c){
  return __builtin_amdgcn_mfma_f32_16x16x32_bf16(a, b, c, 0, 0, 0);
}
// fragment-order LDS layout for a [16 rows x 256 k] bf16 plane:
// 16B unit index = kc*16 + ((row^kc)&15)  -> conflict-free b128 reads/writes
__device__ __forceinline__ int foff(int kc, int row){
  return (kc * 16 + ((row ^ kc) & 15)) * 8;  // element (short) index
}

// ---------------- dtype sniff: t sorted in [0,10]; bf16 u16 <= 0x4120 always.
__global__ void sniff_kernel(const unsigned short* __restrict__ t, int* __restrict__ flag){
  int lane = threadIdx.x & 63;
  int bad = 0;
#pragma unroll
  for (int q = 0; q < 8; ++q)
    if (t[lane * 8 + q] > 0x4200u) bad = 1;
  unsigned long long m = __ballot(bad);
  if (lane == 0) flag[0] = (m != 0ull) ? 1 : 0;
}

// ---------------- canonicalize small weights to bf16
__global__ void conv_kernel(const int* __restrict__ flag,
    const void* __restrict__ Whh, const void* __restrict__ Wih,
    const void* __restrict__ W1,  const void* __restrict__ W2,
    const void* __restrict__ bhh, const void* __restrict__ bih,
    const void* __restrict__ b1,  const void* __restrict__ b2,
    unsigned short* __restrict__ dst)
{
  int i = blockIdx.x * 256 + threadIdx.x;
  if (i >= CANON_N) return;
  int f32m = flag[0];
  const void* src; int off = i;
  if (i < OFF_WIH)      { src = Whh; off = i - OFF_WHH; }
  else if (i < OFF_W1)  { src = Wih; off = i - OFF_WIH; }
  else if (i < OFF_W2)  { src = W1;  off = i - OFF_W1; }
  else if (i < OFF_BHH) { src = W2;  off = i - OFF_W2; }
  else if (i < OFF_BIH) { src = bhh; off = i - OFF_BHH; }
  else if (i < OFF_B1)  { src = bih; off = i - OFF_BIH; }
  else if (i < OFF_B2)  { src = b1;  off = i - OFF_B1; }
  else                  { src = b2;  off = i - OFF_B2; }
  unsigned short v = f32m ? f2bf(((const float*)src)[off])
                          : ((const unsigned short*)src)[off];
  dst[i] = v;
}

// ---------------- W_head -> bf16 (4 elements per thread)
__global__ void convw_kernel(const int* __restrict__ flag,
    const void* __restrict__ Wh, unsigned short* __restrict__ dst)
{
  int i4 = blockIdx.x * 256 + threadIdx.x;
  if (i4 * 4 >= NITEMS * HD) return;
  if (flag[0]){
    f32x4 v = ((const f32x4*)Wh)[i4];
#pragma unroll
    for (int q = 0; q < 4; ++q) dst[i4 * 4 + q] = f2bf(v[q]);
  } else {
    ((unsigned long long*)dst)[i4] = ((const unsigned long long*)Wh)[i4];
  }
}

// ---------------- dt precompute
__global__ void dt_kernel(const void* __restrict__ t, const int* __restrict__ flag,
                          float* __restrict__ dt){
  int i = blockIdx.x * 256 + threadIdx.x;
  if (i >= B_SZ * S_LEN) return;
  int f32m = flag[0];
  int s = i % S_LEN;
  float tc = f32m ? ((const float*)t)[i] : bf2f(((const unsigned short*)t)[i]);
  float d = 0.0f;
  if (s < S_LEN - 1){
    float tn = f32m ? ((const float*)t)[i + 1] : bf2f(((const unsigned short*)t)[i + 1]);
    d = fmaxf(tn, tc + 1e-5f) - tc;
  }
  dt[i] = d;
}

// ---------------- G[i, j] = sum_k emb[i,k] * Wih[j,k] + bih[j]   (i<50000, j<768)
__global__ __launch_bounds__(256) void gitems_kernel(
    const void* __restrict__ emb, const unsigned short* __restrict__ canon,
    const int* __restrict__ flag, void* __restrict__ tbl, int tblf32)
{
  __shared__ __align__(16) short ap[4][4096];    // 4 row-tiles x [16x256] bf16
  const int tid = threadIdx.x;
  const int i0 = blockIdx.x * 64;
  const int n0 = blockIdx.y * 256;
  const int f32m = flag[0];
  {
    int kc = tid & 31, r8 = tid >> 5;
#pragma unroll
    for (int p = 0; p < 8; ++p){
      int row = p * 8 + r8;
      int gr = i0 + row; if (gr > NITEMS - 1) gr = NITEMS - 1;
      short8 v;
      if (f32m){
        const f32x4* src = (const f32x4*)((const float*)emb + gr * HD + kc * 8);
        f32x4 v0 = src[0], v1 = src[1];
#pragma unroll
        for (int q = 0; q < 4; ++q){ v[q] = (short)f2bf(v0[q]); v[4+q] = (short)f2bf(v1[q]); }
      } else {
        v = *(const short8*)((const unsigned short*)emb + gr * HD + kc * 8);
      }
      *(short8*)&ap[row >> 4][foff(kc, row & 15)] = v;
    }
  }
  __syncthreads();
  const int wave = tid >> 6, lane = tid & 63, col = lane & 15, quad = lane >> 4;
  const unsigned short* Wih = canon + OFF_WIH;
  const unsigned short* bih = canon + OFF_BIH;
  f32x4 zz = {0.0f, 0.0f, 0.0f, 0.0f};
  f32x4 acc[4][4];
#pragma unroll
  for (int rt = 0; rt < 4; ++rt)
#pragma unroll
    for (int ct = 0; ct < 4; ++ct) acc[rt][ct] = zz;

#pragma unroll
  for (int ks = 0; ks < 8; ++ks){
    short8 bf[4];
#pragma unroll
    for (int ct = 0; ct < 4; ++ct){
      int n = n0 + wave * 64 + ct * 16 + col;
      bf[ct] = *(const short8*)(Wih + n * HD + ks * 32 + quad * 8);
    }
    int kc = ks * 4 + quad;
#pragma unroll
    for (int rt = 0; rt < 4; ++rt){
      short8 a = *(const short8*)&ap[rt][foff(kc, col)];
#pragma unroll
      for (int ct = 0; ct < 4; ++ct) acc[rt][ct] = MFMA(a, bf[ct], acc[rt][ct]);
    }
  }
  float bv[4];
#pragma unroll
  for (int ct = 0; ct < 4; ++ct) bv[ct] = bf2f(bih[n0 + wave * 64 + ct * 16 + col]);
  float* tfo = (float*)tbl; unsigned short* tbo = (unsigned short*)tbl;
#pragma unroll
  for (int rt = 0; rt < 4; ++rt)
#pragma unroll
    for (int ct = 0; ct < 4; ++ct)
#pragma unroll
      for (int r = 0; r < 4; ++r){
        int row = i0 + rt * 16 + quad * 4 + r;
        if (row < NITEMS){
          int n = n0 + wave * 64 + ct * 16 + col;
          float v = acc[rt][ct][r] + bv[ct];
          if (tblf32) tfo[row * 768 + n] = v;
          else        tbo[row * 768 + n] = (unsigned short)f2bf(v);
        }
      }
}

// ---------------- persistent scan: 64 WGs x 512 thr; WG owns 16 batch rows.
// All weights (Whh, W1, W2) streamed from L2 inside the MFMA loops; register
// pressure kept low so the compiler can batch the 16 independent B-fragment
// loads per stage ahead of the accumulator chain. NT gathers keep weights
// L2-resident (proven in R3: FETCH 1.24 GB -> 0.77 GB).
__global__ __launch_bounds__(512)
void scan_kernel(
    const int* __restrict__ x, const float* __restrict__ dtp,
    const unsigned short* __restrict__ canon,
    const void* __restrict__ tbl, int tblf32,
    float* __restrict__ hstate)
{
  __shared__ __align__(16) short bufhi[2][4096];   // ping-pong A planes (bf16 hi)
  __shared__ __align__(16) short buflo[2][4096];   // lo plane (h state only)
  __shared__ __align__(16) int   xl[16 * S_LEN];   // item indices, staged once
  __shared__ __align__(16) float dtall[16 * S_LEN];// dt, staged once

  const int tid  = threadIdx.x;
  const int wave = tid >> 6;
  const int lane = tid & 63;
  const int col  = lane & 15;        // A-row / C-col lane index
  const int quad = lane >> 4;
  const int r0   = blockIdx.x * 16;  // batch rows owned by this WG
  const int wc0  = wave * 32;        // hidden-col base for this wave (2 tiles of 16)

  const unsigned short* Whh = canon + OFF_WHH;
  const unsigned short* W1w = canon + OFF_W1;
  const unsigned short* W2w = canon + OFF_W2;
  const unsigned short* bhh = canon + OFF_BHH;
  const unsigned short* b1v = canon + OFF_B1;
  const unsigned short* b2v = canon + OFF_B2;

  { // zero initial h buffer (buf 0): h0 = 0
    short8 z = {0,0,0,0,0,0,0,0};
    *(short8*)&bufhi[0][tid * 8] = z;
    *(short8*)&buflo[0][tid * 8] = z;
  }
  // stage x / dt for this WG's 16 rows (contiguous, coalesced)
  for (int i = tid; i < 16 * S_LEN; i += 512){
    xl[i]    = x[r0 * S_LEN + i];
    dtall[i] = dtp[r0 * S_LEN + i];
  }

  float bR[2], bZ[2], bN[2], b1c[2], b2c[2];
#pragma unroll
  for (int ct = 0; ct < 2; ++ct){
    int c = wc0 + ct * 16 + col;
    bR[ct]  = bf2f(bhh[c]);          bZ[ct] = bf2f(bhh[HD + c]);
    bN[ct]  = bf2f(bhh[2 * HD + c]);
    b1c[ct] = bf2f(b1v[c]);          b2c[ct] = bf2f(b2v[c]);
  }

  float h[2][4];
#pragma unroll
  for (int ct = 0; ct < 2; ++ct)
#pragma unroll
    for (int r = 0; r < 4; ++r) h[ct][r] = 0.0f;

  const float* tf = (const float*)tbl;
  const unsigned short* tb = (const unsigned short*)tbl;

  __syncthreads();

  for (int s = 0; s < S_LEN; ++s){
    const int pb = s & 1;
    float dtr[4];
#pragma unroll
    for (int r = 0; r < 4; ++r) dtr[r] = dtall[(quad * 4 + r) * S_LEN + s];

    // ---- stage 0: gh = h @ Whh^T (hi/lo split A), acc pre-init with gathered gi
    f32x4 aR[2], aZ[2], aN[2];
    float giN[2][4];
#pragma unroll
    for (int r = 0; r < 4; ++r){
      int row = quad * 4 + r;
      long base = (long)xl[row * S_LEN + s] * 768;
#pragma unroll
      for (int ct = 0; ct < 2; ++ct){
        int c = wc0 + ct * 16 + col;
        float gr, gz, gn;
        if (tblf32){
          gr = __builtin_nontemporal_load(tf + base + c);
          gz = __builtin_nontemporal_load(tf + base + 256 + c);
          gn = __builtin_nontemporal_load(tf + base + 512 + c);
        } else {
          gr = bf2f(__builtin_nontemporal_load(tb + base + c));
          gz = bf2f(__builtin_nontemporal_load(tb + base + 256 + c));
          gn = bf2f(__builtin_nontemporal_load(tb + base + 512 + c));
        }
        aR[ct][r] = gr; aZ[ct][r] = gz; aN[ct][r] = 0.0f; giN[ct][r] = gn;  // i_n separate: r gates only h-part
      }
    }
#pragma unroll
    for (int ks = 0; ks < 8; ++ks){
      int kc = ks * 4 + quad;
      short8 ahi = *(const short8*)&bufhi[pb][foff(kc, col)];
      short8 alo = *(const short8*)&buflo[pb][foff(kc, col)];
#pragma unroll
      for (int ct = 0; ct < 2; ++ct){
        int nb = wc0 + ct * 16 + col;
        short8 b0 = *(const short8*)(Whh + (0 * HD + nb) * HD + ks * 32 + quad * 8);
        aR[ct] = MFMA(ahi, b0, aR[ct]); aR[ct] = MFMA(alo, b0, aR[ct]);
        short8 b1f = *(const short8*)(Whh + (1 * HD + nb) * HD + ks * 32 + quad * 8);
        aZ[ct] = MFMA(ahi, b1f, aZ[ct]); aZ[ct] = MFMA(alo, b1f, aZ[ct]);
        short8 b2f = *(const short8*)(Whh + (2 * HD + nb) * HD + ks * 32 + quad * 8);
        aN[ct] = MFMA(ahi, b2f, aN[ct]); aN[ct] = MFMA(alo, b2f, aN[ct]);
      }
    }
    // gates + GRU update (fp32)
    float hg[2][4], ksum[2][4];
#pragma unroll
    for (int ct = 0; ct < 2; ++ct)
#pragma unroll
      for (int r = 0; r < 4; ++r){
        int row = quad * 4 + r;
        float rr = fsig(aR[ct][r] + bR[ct]);
        float z_ = fsig(aZ[ct][r] + bZ[ct]);
        float nn = ftanh(giN[ct][r] + rr * (aN[ct][r] + bN[ct]));
        float hgv = (1.0f - z_) * nn + z_ * h[ct][r];
        hg[ct][r] = hgv;
        int c = wc0 + ct * 16 + col;
        bufhi[1 - pb][foff(c >> 3, row) + (c & 7)] = (short)f2bf(hgv);
      }
    __syncthreads();                                   // barrier 1

    // ---- RK4: 4 x (u = tanh(y@W1^T+b1); k = u@W2^T+b2), W1/W2 streamed from L2
#pragma unroll
    for (int j = 0; j < 4; ++j){
      // u-stage: read buf[1-pb], write buf[pb]
      f32x4 ua[2];
      ua[0] = (f32x4){b1c[0], b1c[0], b1c[0], b1c[0]};
      ua[1] = (f32x4){b1c[1], b1c[1], b1c[1], b1c[1]};
#pragma unroll
      for (int ks = 0; ks < 8; ++ks){
        int kc = ks * 4 + quad;
        short8 a = *(const short8*)&bufhi[1 - pb][foff(kc, col)];
#pragma unroll
        for (int ct = 0; ct < 2; ++ct){
          short8 w = *(const short8*)(W1w + (wc0 + ct * 16 + col) * HD + ks * 32 + quad * 8);
          ua[ct] = MFMA(a, w, ua[ct]);
        }
      }
#pragma unroll
      for (int ct = 0; ct < 2; ++ct)
#pragma unroll
        for (int r = 0; r < 4; ++r){
          int row = quad * 4 + r, c = wc0 + ct * 16 + col;
          bufhi[pb][foff(c >> 3, row) + (c & 7)] = (short)f2bf(ftanh(ua[ct][r]));
        }
      __syncthreads();

      // k-stage: read buf[pb], write buf[1-pb]
      f32x4 ka[2];
      ka[0] = (f32x4){b2c[0], b2c[0], b2c[0], b2c[0]};
      ka[1] = (f32x4){b2c[1], b2c[1], b2c[1], b2c[1]};
#pragma unroll
      for (int ks = 0; ks < 8; ++ks){
        int kc = ks * 4 + quad;
        short8 a = *(const short8*)&bufhi[pb][foff(kc, col)];
#pragma unroll
        for (int ct = 0; ct < 2; ++ct){
          short8 w = *(const short8*)(W2w + (wc0 + ct * 16 + col) * HD + ks * 32 + quad * 8);
          ka[ct] = MFMA(a, w, ka[ct]);
        }
      }
#pragma unroll
      for (int ct = 0; ct < 2; ++ct)
#pragma unroll
        for (int r = 0; r < 4; ++r){
          int row = quad * 4 + r;
          float dtv = dtr[r];
          float kv = ka[ct][r];
          int c = wc0 + ct * 16 + col;
          if (j == 0){
            ksum[ct][r] = kv;
            float y = hg[ct][r] + 0.5f * dtv * kv;
            bufhi[1 - pb][foff(c >> 3, row) + (c & 7)] = (short)f2bf(y);
          } else if (j == 1){
            ksum[ct][r] += 2.0f * kv;
            float y = hg[ct][r] + 0.5f * dtv * kv;
            bufhi[1 - pb][foff(c >> 3, row) + (c & 7)] = (short)f2bf(y);
          } else if (j == 2){
            ksum[ct][r] += 2.0f * kv;
            float y = hg[ct][r] + dtv * kv;
            bufhi[1 - pb][foff(c >> 3, row) + (c & 7)] = (short)f2bf(y);
          } else {
            ksum[ct][r] += kv;
            float hn = hg[ct][r] + (dtv * (1.0f / 6.0f)) * ksum[ct][r];
            h[ct][r] = hn;
            unsigned short hh = f2bf(hn);
            float fh = bf2f(hh);
            unsigned short hl = f2bf(hn - fh);       // hi/lo split for next step's gh
            bufhi[1 - pb][foff(c >> 3, row) + (c & 7)] = (short)hh;
            buflo[1 - pb][foff(c >> 3, row) + (c & 7)] = (short)hl;
          }
        }
      __syncthreads();
    }
  }
  // store final h (fp32)
#pragma unroll
  for (int ct = 0; ct < 2; ++ct)
#pragma unroll
    for (int r = 0; r < 4; ++r){
      int row = quad * 4 + r;
      hstate[(r0 + row) * HD + wc0 + ct * 16 + col] = h[ct][r];
    }
}

// ---------------- head: out[b,n] = sum_k h[b,k]*Whead[n,k] + bhead[n]
// out dtype follows flag (fp32 normally, bf16 fallback).
__global__ __launch_bounds__(256) void head_kernel(
    const float* __restrict__ hstate,
    const unsigned short* __restrict__ Whb,   // preconverted bf16 (wbf=1) or null path
    const void* __restrict__ Wh,              // original W_head
    const void* __restrict__ bh, const int* __restrict__ flag, int wbf,
    void* __restrict__ outv)
{
  __shared__ __align__(16) short ahi[4][4096];
  __shared__ __align__(16) short alo[4][4096];
  const int tid = threadIdx.x;
  const int i0 = blockIdx.x * 64;
  const int n0 = blockIdx.y * 256;
  const int f32m = flag[0];
  {
    int kc = tid & 31, r8 = tid >> 5;
#pragma unroll
    for (int p = 0; p < 8; ++p){
      int row = p * 8 + r8;
      const float* src = hstate + (i0 + row) * HD + kc * 8;
      short8 vh, vl;
#pragma unroll
      for (int q = 0; q < 8; ++q){
        float f = src[q];
        unsigned short hb = f2bf(f);
        float fh = bf2f(hb);
        vh[q] = (short)hb; vl[q] = (short)f2bf(f - fh);
      }
      int off = foff(kc, row & 15);
      *(short8*)&ahi[row >> 4][off] = vh;
      *(short8*)&alo[row >> 4][off] = vl;
    }
  }
  __syncthreads();
  const int wave = tid >> 6, lane = tid & 63, col = lane & 15, quad = lane >> 4;
  f32x4 zz = {0.0f, 0.0f, 0.0f, 0.0f};
  f32x4 acc[4][4];
#pragma unroll
  for (int rt = 0; rt < 4; ++rt)
#pragma unroll
    for (int ct = 0; ct < 4; ++ct) acc[rt][ct] = zz;

  int nidx[4];
#pragma unroll
  for (int ct = 0; ct < 4; ++ct){
    int n = n0 + wave * 64 + ct * 16 + col;
    nidx[ct] = (n < NITEMS) ? n : (NITEMS - 1);
  }
#pragma unroll
  for (int ks = 0; ks < 8; ++ks){
    short8 bf[4];
#pragma unroll
    for (int ct = 0; ct < 4; ++ct){
      if (wbf){
        bf[ct] = *(const short8*)(Whb + nidx[ct] * HD + ks * 32 + quad * 8);
      } else if (f32m){
        const f32x4* src = (const f32x4*)((const float*)Wh + nidx[ct] * HD + ks * 32 + quad * 8);
        f32x4 v0 = src[0], v1 = src[1];
        short8 v;
#pragma unroll
        for (int q = 0; q < 4; ++q){ v[q] = (short)f2bf(v0[q]); v[4+q] = (short)f2bf(v1[q]); }
        bf[ct] = v;
      } else {
        bf[ct] = *(const short8*)((const unsigned short*)Wh + nidx[ct] * HD + ks * 32 + quad * 8);
      }
    }
    int kc = ks * 4 + quad;
#pragma unroll
    for (int rt = 0; rt < 4; ++rt){
      short8 xh = *(const short8*)&ahi[rt][foff(kc, col)];
      short8 xl = *(const short8*)&alo[rt][foff(kc, col)];
#pragma unroll
      for (int ct = 0; ct < 4; ++ct){
        acc[rt][ct] = MFMA(xh, bf[ct], acc[rt][ct]);
        acc[rt][ct] = MFMA(xl, bf[ct], acc[rt][ct]);
      }
    }
  }
  float bhv[4];
#pragma unroll
  for (int ct = 0; ct < 4; ++ct)
    bhv[ct] = f32m ? ((const float*)bh)[nidx[ct]] : bf2f(((const unsigned short*)bh)[nidx[ct]]);
  float* outf = (float*)outv;
  unsigned short* outb = (unsigned short*)outv;
#pragma unroll
  for (int rt = 0; rt < 4; ++rt)
#pragma unroll
    for (int ct = 0; ct < 4; ++ct)
#pragma unroll
      for (int r = 0; r < 4; ++r){
        int row = i0 + rt * 16 + quad * 4 + r;
        int n = n0 + wave * 64 + ct * 16 + col;
        if (n < NITEMS){
          float v = acc[rt][ct][r] + bhv[ct];
          long o = (long)row * NITEMS + n;
          if (f32m) outf[o] = v;
          else      outb[o] = (unsigned short)f2bf(v);
        }
      }
}

extern "C" void kernel_launch(void* const* d_in, const int* in_sizes, int n_in,
                              void* d_out, int out_size, void* d_ws, size_t ws_size,
                              hipStream_t stream) {
  const int*  x     = (const int*)d_in[0];
  const void* t     = d_in[1];
  const void* emb   = d_in[2];
  const void* Wih   = d_in[3];
  const void* Whh   = d_in[4];
  const void* bih   = d_in[5];
  const void* bhh   = d_in[6];
  const void* W1    = d_in[7];
  const void* b1    = d_in[8];
  const void* W2    = d_in[9];
  const void* b2    = d_in[10];
  const void* Whead = d_in[11];
  const void* bhead = d_in[12];

  char* ws = (char*)d_ws;
  int*   flag   = (int*)(ws);                              // @0      (4 B)
  float* dtbuf  = (float*)(ws + 4096);                     // 819200 B
  float* hstate = (float*)(ws + (1u << 20));               // 1 MB @ +1MB
  unsigned short* canon = (unsigned short*)(ws + (2u << 20));   // ~1.01 MB @ +2MB
  unsigned short* wheadb = (unsigned short*)(ws + (4u << 20));  // 25.6 MB @ +4MB
  const size_t tbase = 32u << 20;                          // table @ +32MB
  const size_t TBL_F32  = (size_t)NPAD * 768 * 4;          // 153.7 MB
  const size_t TBL_BF16 = (size_t)NPAD * 768 * 2;          // 76.9 MB

  int wbf = (ws_size >= (32u << 20)) ? 1 : 0;
  void* tbl; int tblf32;
  if (ws_size >= tbase + TBL_F32)       { tbl = (void*)(ws + tbase); tblf32 = 1; }
  else if (ws_size >= tbase + TBL_BF16) { tbl = (void*)(ws + tbase); tblf32 = 0; }
  else                                  { tbl = (void*)d_out;        tblf32 = 0; } // d_out(204.8MB fp32) as scratch; head overwrites

  sniff_kernel<<<dim3(1), dim3(64), 0, stream>>>((const unsigned short*)t, flag);
  conv_kernel<<<dim3((CANON_N + 255) / 256), dim3(256), 0, stream>>>(
      flag, Whh, Wih, W1, W2, bhh, bih, b1, b2, canon);
  if (wbf)
    convw_kernel<<<dim3((NITEMS * HD / 4 + 255) / 256), dim3(256), 0, stream>>>(
        flag, Whead, wheadb);
  dt_kernel<<<dim3((B_SZ * S_LEN + 255) / 256), dim3(256), 0, stream>>>(t, flag, dtbuf);
  gitems_kernel<<<dim3(NPAD / 64, 3), dim3(256), 0, stream>>>(emb, canon, flag, tbl, tblf32);
  scan_kernel<<<dim3(64), dim3(512), 0, stream>>>(x, dtbuf, canon, tbl, tblf32, hstate);
  head_kernel<<<dim3(B_SZ / 64, (NITEMS + 255) / 256), dim3(256), 0, stream>>>(
      hstate, wheadb, Whead, bhead, flag, wbf, d_out);
}

// Round 5
// 4546.927 us; speedup vs baseline: 1.2037x; 1.0073x over previous
//
#include <hip/hip_runtime.h>

// DeepM3Model: 200-step GRU+RK4 scan (B=1024,S=200,H=256) + head GEMM to 50000 items.
// Inputs/outputs are fp32 (confirmed: bf16 reads gave NaN; fp32-out decode matches
// round-2 error signature). On-device dtype sniff retained as a safety net.
// Pipeline: sniff -> canon weights to bf16 -> dt -> gi table (item_emb@Wih^T+bih,
// fp32 preferred) -> persistent WG-local scan (64 WGs x 16 batch rows, 9 barriers/step,
// weights streamed from L2 in BATCHED register groups) -> head GEMM.
//
// R5 theory: R4 killed the spills (WRITE 387->31 MB) but scan stayed ~4.3 ms with
// every pipe idle (MFMA 3.5%, VALU 6%, HBM 1%) => the 16 weight loads per MFMA
// stage are issued SERIALLY (load->wait->MFMA, ~250cy each = 4k cy/stage; 9 stages
// ~= the measured 51k cy/step). Fix: source-level load batching. Each stage loads
// its 16 B-fragments into a fully-unrolled static array, then sched_barrier(0)
// pins the batch above the MFMA loop. Stage-0 uses 6 groups of 8 (register cap).
// gi gathers decoupled from acc-init (added at gate time) so gather latency
// overlaps stage-0 MFMAs. NT gathers retained (keep weights L2-resident).

#define B_SZ   1024
#define S_LEN  200
#define HD     256
#define NITEMS 50000
#define NPAD   50048

// canonical weight block offsets (u16 elements)
#define OFF_WHH 0
#define OFF_WIH 196608
#define OFF_W1  393216
#define OFF_W2  458752
#define OFF_BHH 524288
#define OFF_BIH 525056
#define OFF_B1  525824
#define OFF_B2  526080
#define CANON_N 526336

typedef short short8 __attribute__((ext_vector_type(8)));
typedef float f32x4  __attribute__((ext_vector_type(4)));

__device__ __forceinline__ float bf2f(unsigned short u){
  unsigned v = ((unsigned)u) << 16; float f; __builtin_memcpy(&f, &v, 4); return f;
}
__device__ __forceinline__ unsigned short f2bf(float f){
  unsigned u; __builtin_memcpy(&u, &f, 4);
  u += 0x7FFFu + ((u >> 16) & 1u);            // round-to-nearest-even
  return (unsigned short)(u >> 16);
}
__device__ __forceinline__ float fsig(float x){ return 1.0f / (1.0f + __expf(-x)); }
__device__ __forceinline__ float ftanh(float x){
  float e = __expf(-2.0f * fabsf(x));
  float r = (1.0f - e) / (1.0f + e);
  return copysignf(r, x);
}
__device__ __forceinline__ f32x4 MFMA(short8 a, short8 b, f32x4 c){
  return __builtin_amdgcn_mfma_f32_16x16x32_bf16(a, b, c, 0, 0, 0);
}
// fragment-order LDS layout for a [16 rows x 256 k] bf16 plane:
// 16B unit index = kc*16 + ((row^kc)&15)  -> conflict-free b128 reads/writes
__device__ __forceinline__ int foff(int kc, int row){
  return (kc * 16 + ((row ^ kc) & 15)) * 8;  // element (short) index
}

// ---------------- dtype sniff: t sorted in [0,10]; bf16 u16 <= 0x4120 always.
__global__ void sniff_kernel(const unsigned short* __restrict__ t, int* __restrict__ flag){
  int lane = threadIdx.x & 63;
  int bad = 0;
#pragma unroll
  for (int q = 0; q < 8; ++q)
    if (t[lane * 8 + q] > 0x4200u) bad = 1;
  unsigned long long m = __ballot(bad);
  if (lane == 0) flag[0] = (m != 0ull) ? 1 : 0;
}

// ---------------- canonicalize small weights to bf16
__global__ void conv_kernel(const int* __restrict__ flag,
    const void* __restrict__ Whh, const void* __restrict__ Wih,
    const void* __restrict__ W1,  const void* __restrict__ W2,
    const void* __restrict__ bhh, const void* __restrict__ bih,
    const void* __restrict__ b1,  const void* __restrict__ b2,
    unsigned short* __restrict__ dst)
{
  int i = blockIdx.x * 256 + threadIdx.x;
  if (i >= CANON_N) return;
  int f32m = flag[0];
  const void* src; int off = i;
  if (i < OFF_WIH)      { src = Whh; off = i - OFF_WHH; }
  else if (i < OFF_W1)  { src = Wih; off = i - OFF_WIH; }
  else if (i < OFF_W2)  { src = W1;  off = i - OFF_W1; }
  else if (i < OFF_BHH) { src = W2;  off = i - OFF_W2; }
  else if (i < OFF_BIH) { src = bhh; off = i - OFF_BHH; }
  else if (i < OFF_B1)  { src = bih; off = i - OFF_BIH; }
  else if (i < OFF_B2)  { src = b1;  off = i - OFF_B1; }
  else                  { src = b2;  off = i - OFF_B2; }
  unsigned short v = f32m ? f2bf(((const float*)src)[off])
                          : ((const unsigned short*)src)[off];
  dst[i] = v;
}

// ---------------- W_head -> bf16 (4 elements per thread)
__global__ void convw_kernel(const int* __restrict__ flag,
    const void* __restrict__ Wh, unsigned short* __restrict__ dst)
{
  int i4 = blockIdx.x * 256 + threadIdx.x;
  if (i4 * 4 >= NITEMS * HD) return;
  if (flag[0]){
    f32x4 v = ((const f32x4*)Wh)[i4];
#pragma unroll
    for (int q = 0; q < 4; ++q) dst[i4 * 4 + q] = f2bf(v[q]);
  } else {
    ((unsigned long long*)dst)[i4] = ((const unsigned long long*)Wh)[i4];
  }
}

// ---------------- dt precompute
__global__ void dt_kernel(const void* __restrict__ t, const int* __restrict__ flag,
                          float* __restrict__ dt){
  int i = blockIdx.x * 256 + threadIdx.x;
  if (i >= B_SZ * S_LEN) return;
  int f32m = flag[0];
  int s = i % S_LEN;
  float tc = f32m ? ((const float*)t)[i] : bf2f(((const unsigned short*)t)[i]);
  float d = 0.0f;
  if (s < S_LEN - 1){
    float tn = f32m ? ((const float*)t)[i + 1] : bf2f(((const unsigned short*)t)[i + 1]);
    d = fmaxf(tn, tc + 1e-5f) - tc;
  }
  dt[i] = d;
}

// ---------------- G[i, j] = sum_k emb[i,k] * Wih[j,k] + bih[j]   (i<50000, j<768)
__global__ __launch_bounds__(256) void gitems_kernel(
    const void* __restrict__ emb, const unsigned short* __restrict__ canon,
    const int* __restrict__ flag, void* __restrict__ tbl, int tblf32)
{
  __shared__ __align__(16) short ap[4][4096];    // 4 row-tiles x [16x256] bf16
  const int tid = threadIdx.x;
  const int i0 = blockIdx.x * 64;
  const int n0 = blockIdx.y * 256;
  const int f32m = flag[0];
  {
    int kc = tid & 31, r8 = tid >> 5;
#pragma unroll
    for (int p = 0; p < 8; ++p){
      int row = p * 8 + r8;
      int gr = i0 + row; if (gr > NITEMS - 1) gr = NITEMS - 1;
      short8 v;
      if (f32m){
        const f32x4* src = (const f32x4*)((const float*)emb + gr * HD + kc * 8);
        f32x4 v0 = src[0], v1 = src[1];
#pragma unroll
        for (int q = 0; q < 4; ++q){ v[q] = (short)f2bf(v0[q]); v[4+q] = (short)f2bf(v1[q]); }
      } else {
        v = *(const short8*)((const unsigned short*)emb + gr * HD + kc * 8);
      }
      *(short8*)&ap[row >> 4][foff(kc, row & 15)] = v;
    }
  }
  __syncthreads();
  const int wave = tid >> 6, lane = tid & 63, col = lane & 15, quad = lane >> 4;
  const unsigned short* Wih = canon + OFF_WIH;
  const unsigned short* bih = canon + OFF_BIH;
  f32x4 zz = {0.0f, 0.0f, 0.0f, 0.0f};
  f32x4 acc[4][4];
#pragma unroll
  for (int rt = 0; rt < 4; ++rt)
#pragma unroll
    for (int ct = 0; ct < 4; ++ct) acc[rt][ct] = zz;

#pragma unroll
  for (int ks = 0; ks < 8; ++ks){
    short8 bf[4];
#pragma unroll
    for (int ct = 0; ct < 4; ++ct){
      int n = n0 + wave * 64 + ct * 16 + col;
      bf[ct] = *(const short8*)(Wih + n * HD + ks * 32 + quad * 8);
    }
    int kc = ks * 4 + quad;
#pragma unroll
    for (int rt = 0; rt < 4; ++rt){
      short8 a = *(const short8*)&ap[rt][foff(kc, col)];
#pragma unroll
      for (int ct = 0; ct < 4; ++ct) acc[rt][ct] = MFMA(a, bf[ct], acc[rt][ct]);
    }
  }
  float bv[4];
#pragma unroll
  for (int ct = 0; ct < 4; ++ct) bv[ct] = bf2f(bih[n0 + wave * 64 + ct * 16 + col]);
  float* tfo = (float*)tbl; unsigned short* tbo = (unsigned short*)tbl;
#pragma unroll
  for (int rt = 0; rt < 4; ++rt)
#pragma unroll
    for (int ct = 0; ct < 4; ++ct)
#pragma unroll
      for (int r = 0; r < 4; ++r){
        int row = i0 + rt * 16 + quad * 4 + r;
        if (row < NITEMS){
          int n = n0 + wave * 64 + ct * 16 + col;
          float v = acc[rt][ct][r] + bv[ct];
          if (tblf32) tfo[row * 768 + n] = v;
          else        tbo[row * 768 + n] = (unsigned short)f2bf(v);
        }
      }
}

// ---------------- persistent scan: 64 WGs x 512 thr; WG owns 16 batch rows.
// Weight loads BATCHED: each MFMA stage first issues all its B-fragment loads
// into a fully-unrolled register array, then sched_barrier(0) pins the batch
// above the MFMA chain. One L2 round-trip per stage instead of 16.
__global__ __launch_bounds__(512)
void scan_kernel(
    const int* __restrict__ x, const float* __restrict__ dtp,
    const unsigned short* __restrict__ canon,
    const void* __restrict__ tbl, int tblf32,
    float* __restrict__ hstate)
{
  __shared__ __align__(16) short bufhi[2][4096];   // ping-pong A planes (bf16 hi)
  __shared__ __align__(16) short buflo[2][4096];   // lo plane (h state only)
  __shared__ __align__(16) int   xl[16 * S_LEN];   // item indices, staged once
  __shared__ __align__(16) float dtall[16 * S_LEN];// dt, staged once

  const int tid  = threadIdx.x;
  const int wave = tid >> 6;
  const int lane = tid & 63;
  const int col  = lane & 15;        // A-row / C-col lane index
  const int quad = lane >> 4;
  const int r0   = blockIdx.x * 16;  // batch rows owned by this WG
  const int wc0  = wave * 32;        // hidden-col base for this wave (2 tiles of 16)

  const unsigned short* Whh = canon + OFF_WHH;
  const unsigned short* W1w = canon + OFF_W1;
  const unsigned short* W2w = canon + OFF_W2;
  const unsigned short* bhh = canon + OFF_BHH;
  const unsigned short* b1v = canon + OFF_B1;
  const unsigned short* b2v = canon + OFF_B2;

  { // zero initial h buffer (buf 0): h0 = 0
    short8 z = {0,0,0,0,0,0,0,0};
    *(short8*)&bufhi[0][tid * 8] = z;
    *(short8*)&buflo[0][tid * 8] = z;
  }
  // stage x / dt for this WG's 16 rows (contiguous, coalesced)
  for (int i = tid; i < 16 * S_LEN; i += 512){
    xl[i]    = x[r0 * S_LEN + i];
    dtall[i] = dtp[r0 * S_LEN + i];
  }

  float bR[2], bZ[2], bN[2], b1c[2], b2c[2];
#pragma unroll
  for (int ct = 0; ct < 2; ++ct){
    int c = wc0 + ct * 16 + col;
    bR[ct]  = bf2f(bhh[c]);          bZ[ct] = bf2f(bhh[HD + c]);
    bN[ct]  = bf2f(bhh[2 * HD + c]);
    b1c[ct] = bf2f(b1v[c]);          b2c[ct] = bf2f(b2v[c]);
  }

  float h[2][4];
#pragma unroll
  for (int ct = 0; ct < 2; ++ct)
#pragma unroll
    for (int r = 0; r < 4; ++r) h[ct][r] = 0.0f;

  const float* tf = (const float*)tbl;
  const unsigned short* tb = (const unsigned short*)tbl;

  __syncthreads();

  for (int s = 0; s < S_LEN; ++s){
    const int pb = s & 1;
    float dtr[4];
#pragma unroll
    for (int r = 0; r < 4; ++r) dtr[r] = dtall[(quad * 4 + r) * S_LEN + s];

    // ---- gi gathers: issued first, consumed only at gate time (decoupled from
    //      the MFMA accumulators, so their latency hides under stage-0 MFMAs)
    float gRv[2][4], gZv[2][4], gNv[2][4];
#pragma unroll
    for (int r = 0; r < 4; ++r){
      int row = quad * 4 + r;
      long base = (long)xl[row * S_LEN + s] * 768;
#pragma unroll
      for (int ct = 0; ct < 2; ++ct){
        int c = wc0 + ct * 16 + col;
        if (tblf32){
          gRv[ct][r] = __builtin_nontemporal_load(tf + base + c);
          gZv[ct][r] = __builtin_nontemporal_load(tf + base + 256 + c);
          gNv[ct][r] = __builtin_nontemporal_load(tf + base + 512 + c);
        } else {
          gRv[ct][r] = bf2f(__builtin_nontemporal_load(tb + base + c));
          gZv[ct][r] = bf2f(__builtin_nontemporal_load(tb + base + 256 + c));
          gNv[ct][r] = bf2f(__builtin_nontemporal_load(tb + base + 512 + c));
        }
      }
    }

    // ---- stage 0: gh = h @ Whh^T (hi/lo split A), 6 batched groups of 8 loads
    f32x4 aR[2], aZ[2], aN[2];
#pragma unroll
    for (int g = 0; g < 3; ++g){
#pragma unroll
      for (int ct = 0; ct < 2; ++ct){
        short8 wb[8];
#pragma unroll
        for (int ks = 0; ks < 8; ++ks)
          wb[ks] = *(const short8*)(Whh + (g * HD + wc0 + ct * 16 + col) * HD + ks * 32 + quad * 8);
        __builtin_amdgcn_sched_barrier(0);   // pin the load batch above the MFMAs
        f32x4 acc = {0.0f, 0.0f, 0.0f, 0.0f};
#pragma unroll
        for (int ks = 0; ks < 8; ++ks){
          int kc = ks * 4 + quad;
          short8 ahi = *(const short8*)&bufhi[pb][foff(kc, col)];
          short8 alo = *(const short8*)&buflo[pb][foff(kc, col)];
          acc = MFMA(ahi, wb[ks], acc);
          acc = MFMA(alo, wb[ks], acc);
        }
        if (g == 0)      aR[ct] = acc;
        else if (g == 1) aZ[ct] = acc;
        else             aN[ct] = acc;
      }
    }
    // gates + GRU update (fp32); gi added here (decoupled from MFMA chain)
    float hg[2][4], ksum[2][4];
#pragma unroll
    for (int ct = 0; ct < 2; ++ct)
#pragma unroll
      for (int r = 0; r < 4; ++r){
        int row = quad * 4 + r;
        float rr = fsig(aR[ct][r] + gRv[ct][r] + bR[ct]);
        float z_ = fsig(aZ[ct][r] + gZv[ct][r] + bZ[ct]);
        float nn = ftanh(gNv[ct][r] + rr * (aN[ct][r] + bN[ct]));
        float hgv = (1.0f - z_) * nn + z_ * h[ct][r];
        hg[ct][r] = hgv;
        int c = wc0 + ct * 16 + col;
        bufhi[1 - pb][foff(c >> 3, row) + (c & 7)] = (short)f2bf(hgv);
      }
    __syncthreads();                                   // barrier 1

    // ---- RK4: 4 x (u = tanh(y@W1^T+b1); k = u@W2^T+b2), 16-load batches
#pragma unroll
    for (int j = 0; j < 4; ++j){
      // u-stage: read buf[1-pb], write buf[pb]
      short8 w1b[2][8];
#pragma unroll
      for (int ct = 0; ct < 2; ++ct)
#pragma unroll
        for (int ks = 0; ks < 8; ++ks)
          w1b[ct][ks] = *(const short8*)(W1w + (wc0 + ct * 16 + col) * HD + ks * 32 + quad * 8);
      __builtin_amdgcn_sched_barrier(0);
      f32x4 ua[2];
      ua[0] = (f32x4){b1c[0], b1c[0], b1c[0], b1c[0]};
      ua[1] = (f32x4){b1c[1], b1c[1], b1c[1], b1c[1]};
#pragma unroll
      for (int ks = 0; ks < 8; ++ks){
        int kc = ks * 4 + quad;
        short8 a = *(const short8*)&bufhi[1 - pb][foff(kc, col)];
        ua[0] = MFMA(a, w1b[0][ks], ua[0]);
        ua[1] = MFMA(a, w1b[1][ks], ua[1]);
      }
#pragma unroll
      for (int ct = 0; ct < 2; ++ct)
#pragma unroll
        for (int r = 0; r < 4; ++r){
          int row = quad * 4 + r, c = wc0 + ct * 16 + col;
          bufhi[pb][foff(c >> 3, row) + (c & 7)] = (short)f2bf(ftanh(ua[ct][r]));
        }
      __syncthreads();

      // k-stage: read buf[pb], write buf[1-pb]
      short8 w2b[2][8];
#pragma unroll
      for (int ct = 0; ct < 2; ++ct)
#pragma unroll
        for (int ks = 0; ks < 8; ++ks)
          w2b[ct][ks] = *(const short8*)(W2w + (wc0 + ct * 16 + col) * HD + ks * 32 + quad * 8);
      __builtin_amdgcn_sched_barrier(0);
      f32x4 ka[2];
      ka[0] = (f32x4){b2c[0], b2c[0], b2c[0], b2c[0]};
      ka[1] = (f32x4){b2c[1], b2c[1], b2c[1], b2c[1]};
#pragma unroll
      for (int ks = 0; ks < 8; ++ks){
        int kc = ks * 4 + quad;
        short8 a = *(const short8*)&bufhi[pb][foff(kc, col)];
        ka[0] = MFMA(a, w2b[0][ks], ka[0]);
        ka[1] = MFMA(a, w2b[1][ks], ka[1]);
      }
#pragma unroll
      for (int ct = 0; ct < 2; ++ct)
#pragma unroll
        for (int r = 0; r < 4; ++r){
          int row = quad * 4 + r;
          float dtv = dtr[r];
          float kv = ka[ct][r];
          int c = wc0 + ct * 16 + col;
          if (j == 0){
            ksum[ct][r] = kv;
            float y = hg[ct][r] + 0.5f * dtv * kv;
            bufhi[1 - pb][foff(c >> 3, row) + (c & 7)] = (short)f2bf(y);
          } else if (j == 1){
            ksum[ct][r] += 2.0f * kv;
            float y = hg[ct][r] + 0.5f * dtv * kv;
            bufhi[1 - pb][foff(c >> 3, row) + (c & 7)] = (short)f2bf(y);
          } else if (j == 2){
            ksum[ct][r] += 2.0f * kv;
            float y = hg[ct][r] + dtv * kv;
            bufhi[1 - pb][foff(c >> 3, row) + (c & 7)] = (short)f2bf(y);
          } else {
            ksum[ct][r] += kv;
            float hn = hg[ct][r] + (dtv * (1.0f / 6.0f)) * ksum[ct][r];
            h[ct][r] = hn;
            unsigned short hh = f2bf(hn);
            float fh = bf2f(hh);
            unsigned short hl = f2bf(hn - fh);       // hi/lo split for next step's gh
            bufhi[1 - pb][foff(c >> 3, row) + (c & 7)] = (short)hh;
            buflo[1 - pb][foff(c >> 3, row) + (c & 7)] = (short)hl;
          }
        }
      __syncthreads();
    }
  }
  // store final h (fp32)
#pragma unroll
  for (int ct = 0; ct < 2; ++ct)
#pragma unroll
    for (int r = 0; r < 4; ++r){
      int row = quad * 4 + r;
      hstate[(r0 + row) * HD + wc0 + ct * 16 + col] = h[ct][r];
    }
}

// ---------------- head: out[b,n] = sum_k h[b,k]*Whead[n,k] + bhead[n]
// out dtype follows flag (fp32 normally, bf16 fallback).
__global__ __launch_bounds__(256) void head_kernel(
    const float* __restrict__ hstate,
    const unsigned short* __restrict__ Whb,   // preconverted bf16 (wbf=1) or null path
    const void* __restrict__ Wh,              // original W_head
    const void* __restrict__ bh, const int* __restrict__ flag, int wbf,
    void* __restrict__ outv)
{
  __shared__ __align__(16) short ahi[4][4096];
  __shared__ __align__(16) short alo[4][4096];
  const int tid = threadIdx.x;
  const int i0 = blockIdx.x * 64;
  const int n0 = blockIdx.y * 256;
  const int f32m = flag[0];
  {
    int kc = tid & 31, r8 = tid >> 5;
#pragma unroll
    for (int p = 0; p < 8; ++p){
      int row = p * 8 + r8;
      const float* src = hstate + (i0 + row) * HD + kc * 8;
      short8 vh, vl;
#pragma unroll
      for (int q = 0; q < 8; ++q){
        float f = src[q];
        unsigned short hb = f2bf(f);
        float fh = bf2f(hb);
        vh[q] = (short)hb; vl[q] = (short)f2bf(f - fh);
      }
      int off = foff(kc, row & 15);
      *(short8*)&ahi[row >> 4][off] = vh;
      *(short8*)&alo[row >> 4][off] = vl;
    }
  }
  __syncthreads();
  const int wave = tid >> 6, lane = tid & 63, col = lane & 15, quad = lane >> 4;
  f32x4 zz = {0.0f, 0.0f, 0.0f, 0.0f};
  f32x4 acc[4][4];
#pragma unroll
  for (int rt = 0; rt < 4; ++rt)
#pragma unroll
    for (int ct = 0; ct < 4; ++ct) acc[rt][ct] = zz;

  int nidx[4];
#pragma unroll
  for (int ct = 0; ct < 4; ++ct){
    int n = n0 + wave * 64 + ct * 16 + col;
    nidx[ct] = (n < NITEMS) ? n : (NITEMS - 1);
  }
#pragma unroll
  for (int ks = 0; ks < 8; ++ks){
    short8 bf[4];
#pragma unroll
    for (int ct = 0; ct < 4; ++ct){
      if (wbf){
        bf[ct] = *(const short8*)(Whb + nidx[ct] * HD + ks * 32 + quad * 8);
      } else if (f32m){
        const f32x4* src = (const f32x4*)((const float*)Wh + nidx[ct] * HD + ks * 32 + quad * 8);
        f32x4 v0 = src[0], v1 = src[1];
        short8 v;
#pragma unroll
        for (int q = 0; q < 4; ++q){ v[q] = (short)f2bf(v0[q]); v[4+q] = (short)f2bf(v1[q]); }
        bf[ct] = v;
      } else {
        bf[ct] = *(const short8*)((const unsigned short*)Wh + nidx[ct] * HD + ks * 32 + quad * 8);
      }
    }
    int kc = ks * 4 + quad;
#pragma unroll
    for (int rt = 0; rt < 4; ++rt){
      short8 xh = *(const short8*)&ahi[rt][foff(kc, col)];
      short8 xl = *(const short8*)&alo[rt][foff(kc, col)];
#pragma unroll
      for (int ct = 0; ct < 4; ++ct){
        acc[rt][ct] = MFMA(xh, bf[ct], acc[rt][ct]);
        acc[rt][ct] = MFMA(xl, bf[ct], acc[rt][ct]);
      }
    }
  }
  float bhv[4];
#pragma unroll
  for (int ct = 0; ct < 4; ++ct)
    bhv[ct] = f32m ? ((const float*)bh)[nidx[ct]] : bf2f(((const unsigned short*)bh)[nidx[ct]]);
  float* outf = (float*)outv;
  unsigned short* outb = (unsigned short*)outv;
#pragma unroll
  for (int rt = 0; rt < 4; ++rt)
#pragma unroll
    for (int ct = 0; ct < 4; ++ct)
#pragma unroll
      for (int r = 0; r < 4; ++r){
        int row = i0 + rt * 16 + quad * 4 + r;
        int n = n0 + wave * 64 + ct * 16 + col;
        if (n < NITEMS){
          float v = acc[rt][ct][r] + bhv[ct];
          long o = (long)row * NITEMS + n;
          if (f32m) outf[o] = v;
          else      outb[o] = (unsigned short)f2bf(v);
        }
      }
}

extern "C" void kernel_launch(void* const* d_in, const int* in_sizes, int n_in,
                              void* d_out, int out_size, void* d_ws, size_t ws_size,
                              hipStream_t stream) {
  const int*  x     = (const int*)d_in[0];
  const void* t     = d_in[1];
  const void* emb   = d_in[2];
  const void* Wih   = d_in[3];
  const void* Whh   = d_in[4];
  const void* bih   = d_in[5];
  const void* bhh   = d_in[6];
  const void* W1    = d_in[7];
  const void* b1    = d_in[8];
  const void* W2    = d_in[9];
  const void* b2    = d_in[10];
  const void* Whead = d_in[11];
  const void* bhead = d_in[12];

  char* ws = (char*)d_ws;
  int*   flag   = (int*)(ws);                              // @0      (4 B)
  float* dtbuf  = (float*)(ws + 4096);                     // 819200 B
  float* hstate = (float*)(ws + (1u << 20));               // 1 MB @ +1MB
  unsigned short* canon = (unsigned short*)(ws + (2u << 20));   // ~1.01 MB @ +2MB
  unsigned short* wheadb = (unsigned short*)(ws + (4u << 20));  // 25.6 MB @ +4MB
  const size_t tbase = 32u << 20;                          // table @ +32MB
  const size_t TBL_F32  = (size_t)NPAD * 768 * 4;          // 153.7 MB
  const size_t TBL_BF16 = (size_t)NPAD * 768 * 2;          // 76.9 MB

  int wbf = (ws_size >= (32u << 20)) ? 1 : 0;
  void* tbl; int tblf32;
  if (ws_size >= tbase + TBL_F32)       { tbl = (void*)(ws + tbase); tblf32 = 1; }
  else if (ws_size >= tbase + TBL_BF16) { tbl = (void*)(ws + tbase); tblf32 = 0; }
  else                                  { tbl = (void*)d_out;        tblf32 = 0; } // d_out(204.8MB fp32) as scratch; head overwrites

  sniff_kernel<<<dim3(1), dim3(64), 0, stream>>>((const unsigned short*)t, flag);
  conv_kernel<<<dim3((CANON_N + 255) / 256), dim3(256), 0, stream>>>(
      flag, Whh, Wih, W1, W2, bhh, bih, b1, b2, canon);
  if (wbf)
    convw_kernel<<<dim3((NITEMS * HD / 4 + 255) / 256), dim3(256), 0, stream>>>(
        flag, Whead, wheadb);
  dt_kernel<<<dim3((B_SZ * S_LEN + 255) / 256), dim3(256), 0, stream>>>(t, flag, dtbuf);
  gitems_kernel<<<dim3(NPAD / 64, 3), dim3(256), 0, stream>>>(emb, canon, flag, tbl, tblf32);
  scan_kernel<<<dim3(64), dim3(512), 0, stream>>>(x, dtbuf, canon, tbl, tblf32, hstate);
  head_kernel<<<dim3(B_SZ / 64, (NITEMS + 255) / 256), dim3(256), 0, stream>>>(
      hstate, wheadb, Whead, bhead, flag, wbf, d_out);
}